// Round 1
// baseline (111.568 us; speedup 1.0000x reference)
//
#include <hip/hip_runtime.h>
#include <cstdint>
#include <cstddef>

typedef __attribute__((ext_vector_type(8))) short short8;
typedef __attribute__((ext_vector_type(8))) unsigned short ushort8;
typedef __attribute__((ext_vector_type(4))) float f32x4;

#define AS1Q const __attribute__((address_space(1)))
#define AS3Q __attribute__((address_space(3)))

constexpr int T_N = 60, IN_N = 520, MOE_RAW_N = 512, MOE_IN_N = 992;
constexpr int HID_N = 752, E_N = 8;
constexpr int K1_N = 7936, K2_N = 6016;   // 8*992, 8*752
constexpr int SPLITK = 20;

static __device__ __forceinline__ unsigned short f2bf(float f) {
  unsigned int u = __float_as_uint(f);
  return (unsigned short)((u + 0x7fffu + ((u >> 16) & 1u)) >> 16);   // RNE
}
static __device__ __forceinline__ float sigf(float x) {
  return __fdividef(1.f, 1.f + __expf(-x));
}
static __device__ __forceinline__ float tanh_fast(float x) {
  return 2.f * __fdividef(1.f, 1.f + __expf(-2.f * x)) - 1.f;
}

// ---------------------------------------------------------------------------
// GRU (2 layers, H=8) -> Omega = softmax(h2[:, -1, :]).
// 8 lanes per sample (one per hidden unit), 8 samples per wave.
// ---------------------------------------------------------------------------
__global__ __launch_bounds__(64)
void gru_omega_kernel(const float* __restrict__ X,
                      const float* __restrict__ Wih0, const float* __restrict__ Whh0,
                      const float* __restrict__ bih0, const float* __restrict__ bhh0,
                      const float* __restrict__ Wih1, const float* __restrict__ Whh1,
                      const float* __restrict__ bih1, const float* __restrict__ bhh1,
                      float* __restrict__ Omega)
{
  const int lane = threadIdx.x;
  const int j = lane & 7;          // hidden unit
  const int base = lane & 56;      // 8-lane group base
  const int b = blockIdx.x * 8 + (lane >> 3);

  float wi0r[8], wi0z[8], wi0n[8], wh0r[8], wh0z[8], wh0n[8];
  float wi1r[8], wi1z[8], wi1n[8], wh1r[8], wh1z[8], wh1n[8];
#pragma unroll
  for (int i = 0; i < 8; ++i) {
    wi0r[i] = Wih0[j * 8 + i]; wi0z[i] = Wih0[(8 + j) * 8 + i]; wi0n[i] = Wih0[(16 + j) * 8 + i];
    wh0r[i] = Whh0[j * 8 + i]; wh0z[i] = Whh0[(8 + j) * 8 + i]; wh0n[i] = Whh0[(16 + j) * 8 + i];
    wi1r[i] = Wih1[j * 8 + i]; wi1z[i] = Wih1[(8 + j) * 8 + i]; wi1n[i] = Wih1[(16 + j) * 8 + i];
    wh1r[i] = Whh1[j * 8 + i]; wh1z[i] = Whh1[(8 + j) * 8 + i]; wh1n[i] = Whh1[(16 + j) * 8 + i];
  }
  const float br0 = bih0[j] + bhh0[j], bz0 = bih0[8 + j] + bhh0[8 + j];
  const float bin0 = bih0[16 + j],     bhn0 = bhh0[16 + j];
  const float br1 = bih1[j] + bhh1[j], bz1 = bih1[8 + j] + bhh1[8 + j];
  const float bin1 = bih1[16 + j],     bhn1 = bhh1[16 + j];

  float h1 = 0.f, h2 = 0.f;
  const float* xb = X + (size_t)b * (T_N * IN_N) + MOE_RAW_N;

  for (int t = 0; t < T_N; ++t) {
    float x = xb[t * IN_N + j];
    float gr = br0, gz = bz0, gn = bin0, hn = bhn0;
#pragma unroll
    for (int i = 0; i < 8; ++i) {
      float xi = __shfl(x, base + i);
      gr += wi0r[i] * xi; gz += wi0z[i] * xi; gn += wi0n[i] * xi;
    }
#pragma unroll
    for (int i = 0; i < 8; ++i) {
      float hv = __shfl(h1, base + i);
      gr += wh0r[i] * hv; gz += wh0z[i] * hv; hn += wh0n[i] * hv;
    }
    float r = sigf(gr), z = sigf(gz);
    float n = tanh_fast(gn + r * hn);
    h1 = (1.f - z) * n + z * h1;

    gr = br1; gz = bz1; gn = bin1; hn = bhn1;
#pragma unroll
    for (int i = 0; i < 8; ++i) {
      float xi = __shfl(h1, base + i);
      gr += wi1r[i] * xi; gz += wi1z[i] * xi; gn += wi1n[i] * xi;
    }
#pragma unroll
    for (int i = 0; i < 8; ++i) {
      float hv = __shfl(h2, base + i);
      gr += wh1r[i] * hv; gz += wh1z[i] * hv; hn += wh1n[i] * hv;
    }
    r = sigf(gr); z = sigf(gz);
    n = tanh_fast(gn + r * hn);
    h2 = (1.f - z) * n + z * h2;
  }

  // softmax over the 8-lane group
  float m = h2;
#pragma unroll
  for (int d = 1; d < 8; d <<= 1) m = fmaxf(m, __shfl_xor(m, d));
  float e = __expf(h2 - m);
  float s = e;
#pragma unroll
  for (int d = 1; d < 8; d <<= 1) s += __shfl_xor(s, d);
  Omega[b * 8 + j] = __fdividef(e, s);
}

// ---------------------------------------------------------------------------
// Build x~1[b, (e*992+i) ^ swz] = bf16(Omega[b,e] * Xm[b,i])  (swizzled bf16)
// Xm[b,i] = X[b,59,i] (i<512) else X[b,(i-512)/8, 512+(i-512)%8]
// ---------------------------------------------------------------------------
__global__ __launch_bounds__(256)
void mix1_kernel(const float* __restrict__ X, const float* __restrict__ Omega,
                 unsigned short* __restrict__ xt1)
{
  const int idx = blockIdx.x * 256 + threadIdx.x;      // 256*992 total
  const int b = idx / MOE_IN_N;
  const int i = idx - b * MOE_IN_N;
  const float* Xb = X + (size_t)b * (T_N * IN_N);
  float xm;
  if (i < MOE_RAW_N) {
    xm = Xb[(T_N - 1) * IN_N + i];
  } else {
    const int t = (i - MOE_RAW_N) >> 3, g = (i - MOE_RAW_N) & 7;
    xm = Xb[t * IN_N + MOE_RAW_N + g];
  }
  const int swz = (b & 7) << 3;
  unsigned short* row = xt1 + (size_t)b * K1_N;
#pragma unroll
  for (int e = 0; e < 8; ++e) {
    float w = Omega[b * 8 + e];
    row[(e * MOE_IN_N + i) ^ swz] = f2bf(w * xm);
  }
}

// ---------------------------------------------------------------------------
// Split-K GEMM: P[sp][256][NPAD] += A(bf16, swizzled [256][K]) * Bw(fp32 [K][N])
// BM=256 (full M), BN=64, BK=64, 4 waves, wave = 64 rows x 64 cols.
// A staged via global_load_lds (16B), B reg-staged fp32->bf16, transposed,
// XOR-swizzled LDS ( chunk ^= row&7 within 128B rows ).
// ---------------------------------------------------------------------------
__global__ __launch_bounds__(256)
void gemm_splitk(const unsigned short* __restrict__ A,
                 const float* __restrict__ Bw,
                 float* __restrict__ P,
                 int K, int N, int NPAD)
{
  __shared__ unsigned short Al[2][256][64];   // 64 KB
  __shared__ unsigned short Bl[2][64][64];    // 16 KB  (Bl[n][k], transposed)

  const int tid = threadIdx.x;
  const int lane = tid & 63;
  const int wave = tid >> 6;
  const int nt = blockIdx.x, sp = blockIdx.y;
  const int n0 = nt * 64;
  const int KT = K >> 6;
  const int kt0 = (KT * sp) / SPLITK;
  const int kt1 = (KT * (sp + 1)) / SPLITK;

  const int r15 = lane & 15, hi4 = lane >> 4, r7 = lane & 7;

  // A staging: each wave stages its own 64 rows, 8 gload_lds per K-tile
  const unsigned short* Abase = A + (size_t)(wave * 64 + (lane >> 3)) * K + (lane & 7) * 8;
  // B staging: thread t -> col n=t&63, k-quarter kq=t>>6 (16 consecutive k)
  const int bn = lane;
  const int kq = wave;
  const bool nvalid = (n0 + bn) < N;
  const float* Bbase = Bw + (size_t)(kq * 16) * N + (n0 + bn);

  f32x4 acc[4][4];
  const f32x4 zero4 = {0.f, 0.f, 0.f, 0.f};
#pragma unroll
  for (int mi = 0; mi < 4; ++mi)
#pragma unroll
    for (int ni = 0; ni < 4; ++ni) acc[mi][ni] = zero4;

  auto stage = [&](int bufi, int kt) {
    const unsigned short* ga = Abase + kt * 64;
#pragma unroll
    for (int it = 0; it < 8; ++it) {
      __builtin_amdgcn_global_load_lds(
          (AS1Q unsigned int*)(ga + (size_t)it * 8 * K),
          (AS3Q unsigned int*)&Al[bufi][wave * 64 + it * 8][0],
          16, 0, 0);
    }
    const float* gb = Bbase + (size_t)kt * 64 * N;
    float v[16];
#pragma unroll
    for (int jj = 0; jj < 16; ++jj) v[jj] = nvalid ? gb[(size_t)jj * N] : 0.f;
    ushort8 p0, p1;
#pragma unroll
    for (int jj = 0; jj < 8; ++jj) { p0[jj] = f2bf(v[jj]); p1[jj] = f2bf(v[jj + 8]); }
    const int sl0 = ((kq * 2) ^ (bn & 7)) * 8;       // 8-elem (16B) chunk slots
    const int sl1 = ((kq * 2 + 1) ^ (bn & 7)) * 8;
    *(ushort8*)&Bl[bufi][bn][sl0] = p0;
    *(ushort8*)&Bl[bufi][bn][sl1] = p1;
  };

  auto compute = [&](int bufi) {
#pragma unroll
    for (int ki = 0; ki < 2; ++ki) {
      const int ch = ((ki * 4 + hi4) ^ r7) * 8;      // un-swizzle on read
      short8 af[4], bfv[4];
#pragma unroll
      for (int mi = 0; mi < 4; ++mi)
        af[mi] = *(const short8*)&Al[bufi][wave * 64 + mi * 16 + r15][ch];
#pragma unroll
      for (int ni = 0; ni < 4; ++ni)
        bfv[ni] = *(const short8*)&Bl[bufi][ni * 16 + r15][ch];
#pragma unroll
      for (int mi = 0; mi < 4; ++mi)
#pragma unroll
        for (int ni = 0; ni < 4; ++ni)
          acc[mi][ni] = __builtin_amdgcn_mfma_f32_16x16x32_bf16(af[mi], bfv[ni], acc[mi][ni], 0, 0, 0);
    }
  };

  stage(0, kt0);
  __syncthreads();
  int buf = 0;
  for (int kt = kt0; kt < kt1; ++kt) {
    if (kt + 1 < kt1) stage(buf ^ 1, kt + 1);
    compute(buf);
    __syncthreads();
    buf ^= 1;
  }

  // C/D layout: col = lane&15, row = (lane>>4)*4 + rr   [m89-verified]
  float* Pp = P + (size_t)sp * 256 * NPAD + n0;
#pragma unroll
  for (int mi = 0; mi < 4; ++mi) {
    const int row = wave * 64 + mi * 16 + hi4 * 4;
#pragma unroll
    for (int ni = 0; ni < 4; ++ni) {
#pragma unroll
      for (int rr = 0; rr < 4; ++rr)
        Pp[(size_t)(row + rr) * NPAD + ni * 16 + r15] = acc[mi][ni][rr];
    }
  }
}

// ---------------------------------------------------------------------------
// Reduce split-K partials + Omega-blended bias; then either
//  - ELU + write swizzled bf16 mixed input for next layer (xnext != nullptr)
//  - or write final fp32 output (Yout != nullptr)
// ---------------------------------------------------------------------------
__global__ __launch_bounds__(256)
void reduce_mix_kernel(const float* __restrict__ P, const float* __restrict__ Omega,
                       const float* __restrict__ bias, unsigned short* __restrict__ xnext,
                       float* __restrict__ Yout, int N, int NPAD)
{
  const int n = blockIdx.x * 256 + threadIdx.x;
  const int b = blockIdx.y;
  if (n >= N) return;
  float acc = 0.f;
#pragma unroll 4
  for (int s = 0; s < SPLITK; ++s) acc += P[((size_t)s * 256 + b) * NPAD + n];
  float om[8];
#pragma unroll
  for (int e = 0; e < 8; ++e) om[e] = Omega[b * 8 + e];
  float bs = 0.f;
#pragma unroll
  for (int e = 0; e < 8; ++e) bs += om[e] * bias[(size_t)e * N + n];
  float y = acc + bs;
  if (Yout) { Yout[(size_t)b * N + n] = y; return; }
  float a = (y > 0.f) ? y : expm1f(y);            // ELU
  const int swz = (b & 7) << 3;
  unsigned short* row = xnext + (size_t)b * K2_N;
#pragma unroll
  for (int e = 0; e < 8; ++e)
    row[(e * HID_N + n) ^ swz] = f2bf(om[e] * a);
}

// ---------------------------------------------------------------------------
extern "C" void kernel_launch(void* const* d_in, const int* in_sizes, int n_in,
                              void* d_out, int out_size, void* d_ws, size_t ws_size,
                              hipStream_t stream) {
  const float* X    = (const float*)d_in[0];
  const float* Wih0 = (const float*)d_in[1];
  const float* Whh0 = (const float*)d_in[2];
  const float* bih0 = (const float*)d_in[3];
  const float* bhh0 = (const float*)d_in[4];
  const float* Wih1 = (const float*)d_in[5];
  const float* Whh1 = (const float*)d_in[6];
  const float* bih1 = (const float*)d_in[7];
  const float* bhh1 = (const float*)d_in[8];
  const float* w1   = (const float*)d_in[9];
  const float* b1   = (const float*)d_in[10];
  const float* w2   = (const float*)d_in[11];
  const float* b2   = (const float*)d_in[12];
  const float* w3   = (const float*)d_in[13];
  const float* b3   = (const float*)d_in[14];

  char* ws = (char*)d_ws;
  float* Omega        = (float*)ws;                                  // 8 KB
  unsigned short* xt1 = (unsigned short*)(ws + 8192);                // 256*7936*2 = 4,063,232
  unsigned short* xt2 = (unsigned short*)(ws + 8192 + 4063232);      // 256*6016*2 = 3,080,192
  unsigned short* xt3 = (unsigned short*)(ws + 8192 + 4063232 + 3080192);
  float* P            = (float*)(ws + 8192 + 4063232 + 3080192 + 3080192); // 20*256*768*4 = 15,728,640

  gru_omega_kernel<<<32, 64, 0, stream>>>(X, Wih0, Whh0, bih0, bhh0,
                                          Wih1, Whh1, bih1, bhh1, Omega);
  mix1_kernel<<<992, 256, 0, stream>>>(X, Omega, xt1);

  // layer 1: 256 x 7936 @ 7936 x 752
  gemm_splitk<<<dim3(12, SPLITK), 256, 0, stream>>>(xt1, w1, P, K1_N, HID_N, 768);
  reduce_mix_kernel<<<dim3(3, 256), 256, 0, stream>>>(P, Omega, b1, xt2, nullptr, HID_N, 768);

  // layer 2: 256 x 6016 @ 6016 x 752
  gemm_splitk<<<dim3(12, SPLITK), 256, 0, stream>>>(xt2, w2, P, K2_N, HID_N, 768);
  reduce_mix_kernel<<<dim3(3, 256), 256, 0, stream>>>(P, Omega, b2, xt3, nullptr, HID_N, 768);

  // layer 3: 256 x 6016 @ 6016 x 512
  gemm_splitk<<<dim3(8, SPLITK), 256, 0, stream>>>(xt3, w3, P, K2_N, 512, 512);
  reduce_mix_kernel<<<dim3(2, 256), 256, 0, stream>>>(P, Omega, b3, nullptr, (float*)d_out, 512, 512);
}

// Round 2
// 104.298 us; speedup vs baseline: 1.0697x; 1.0697x over previous
//
#include <hip/hip_runtime.h>
#include <cstdint>
#include <cstddef>

typedef __attribute__((ext_vector_type(8))) short short8;
typedef __attribute__((ext_vector_type(8))) unsigned short ushort8;
typedef __attribute__((ext_vector_type(4))) float f32x4;

#define AS1Q const __attribute__((address_space(1)))
#define AS3Q __attribute__((address_space(3)))

constexpr int T_N = 60, IN_N = 520, MOE_RAW_N = 512, MOE_IN_N = 992;
constexpr int HID_N = 752, E_N = 8;
constexpr int K1_N = 7936, K2_N = 6016;   // 8*992, 8*752
constexpr int SPLITK = 20;

static __device__ __forceinline__ unsigned short f2bf(float f) {
  unsigned int u = __float_as_uint(f);
  return (unsigned short)((u + 0x7fffu + ((u >> 16) & 1u)) >> 16);   // RNE
}
static __device__ __forceinline__ float sigf(float x) {
  return __fdividef(1.f, 1.f + __expf(-x));
}
static __device__ __forceinline__ float tanh_fast(float x) {
  return 2.f * __fdividef(1.f, 1.f + __expf(-2.f * x)) - 1.f;
}

// ---------------------------------------------------------------------------
// GRU (2 layers, H=8) -> Omega = softmax(h2[:, -1, :]).
// 8 lanes per sample (one per hidden unit), 8 samples per wave.
// All 60 timesteps of the gate input slice are prefetched into registers
// BEFORE the serial loop (fully unrolled -> compile-time indexing), so the
// 60-step dependency chain contains no global-memory latency.
// ---------------------------------------------------------------------------
__global__ __launch_bounds__(64)
void gru_omega_kernel(const float* __restrict__ X,
                      const float* __restrict__ Wih0, const float* __restrict__ Whh0,
                      const float* __restrict__ bih0, const float* __restrict__ bhh0,
                      const float* __restrict__ Wih1, const float* __restrict__ Whh1,
                      const float* __restrict__ bih1, const float* __restrict__ bhh1,
                      float* __restrict__ Omega)
{
  const int lane = threadIdx.x;
  const int j = lane & 7;          // hidden unit
  const int base = lane & 56;      // 8-lane group base
  const int b = blockIdx.x * 8 + (lane >> 3);

  const float* xb = X + (size_t)b * (T_N * IN_N) + MOE_RAW_N;

  // ---- prefetch all 60 gate inputs for this lane's column j ----
  float xr[T_N];
#pragma unroll
  for (int t = 0; t < T_N; ++t) xr[t] = xb[t * IN_N + j];

  float wi0r[8], wi0z[8], wi0n[8], wh0r[8], wh0z[8], wh0n[8];
  float wi1r[8], wi1z[8], wi1n[8], wh1r[8], wh1z[8], wh1n[8];
#pragma unroll
  for (int i = 0; i < 8; ++i) {
    wi0r[i] = Wih0[j * 8 + i]; wi0z[i] = Wih0[(8 + j) * 8 + i]; wi0n[i] = Wih0[(16 + j) * 8 + i];
    wh0r[i] = Whh0[j * 8 + i]; wh0z[i] = Whh0[(8 + j) * 8 + i]; wh0n[i] = Whh0[(16 + j) * 8 + i];
    wi1r[i] = Wih1[j * 8 + i]; wi1z[i] = Wih1[(8 + j) * 8 + i]; wi1n[i] = Wih1[(16 + j) * 8 + i];
    wh1r[i] = Whh1[j * 8 + i]; wh1z[i] = Whh1[(8 + j) * 8 + i]; wh1n[i] = Whh1[(16 + j) * 8 + i];
  }
  const float br0 = bih0[j] + bhh0[j], bz0 = bih0[8 + j] + bhh0[8 + j];
  const float bin0 = bih0[16 + j],     bhn0 = bhh0[16 + j];
  const float br1 = bih1[j] + bhh1[j], bz1 = bih1[8 + j] + bhh1[8 + j];
  const float bin1 = bih1[16 + j],     bhn1 = bhh1[16 + j];

  float h1 = 0.f, h2 = 0.f;

#pragma unroll
  for (int t = 0; t < T_N; ++t) {
    float x = xr[t];
    float gr = br0, gz = bz0, gn = bin0, hn = bhn0;
#pragma unroll
    for (int i = 0; i < 8; ++i) {
      float xi = __shfl(x, base + i);
      gr += wi0r[i] * xi; gz += wi0z[i] * xi; gn += wi0n[i] * xi;
    }
#pragma unroll
    for (int i = 0; i < 8; ++i) {
      float hv = __shfl(h1, base + i);
      gr += wh0r[i] * hv; gz += wh0z[i] * hv; hn += wh0n[i] * hv;
    }
    float r = sigf(gr), z = sigf(gz);
    float n = tanh_fast(gn + r * hn);
    h1 = (1.f - z) * n + z * h1;

    gr = br1; gz = bz1; gn = bin1; hn = bhn1;
#pragma unroll
    for (int i = 0; i < 8; ++i) {
      float xi = __shfl(h1, base + i);
      gr += wi1r[i] * xi; gz += wi1z[i] * xi; gn += wi1n[i] * xi;
    }
#pragma unroll
    for (int i = 0; i < 8; ++i) {
      float hv = __shfl(h2, base + i);
      gr += wh1r[i] * hv; gz += wh1z[i] * hv; hn += wh1n[i] * hv;
    }
    r = sigf(gr); z = sigf(gz);
    n = tanh_fast(gn + r * hn);
    h2 = (1.f - z) * n + z * h2;
  }

  // softmax over the 8-lane group
  float m = h2;
#pragma unroll
  for (int d = 1; d < 8; d <<= 1) m = fmaxf(m, __shfl_xor(m, d));
  float e = __expf(h2 - m);
  float s = e;
#pragma unroll
  for (int d = 1; d < 8; d <<= 1) s += __shfl_xor(s, d);
  Omega[b * 8 + j] = __fdividef(e, s);
}

// ---------------------------------------------------------------------------
// Build x~1[b, (e*992+i) ^ swz] = bf16(Omega[b,e] * Xm[b,i])  (swizzled bf16)
// Xm[b,i] = X[b,59,i] (i<512) else X[b,(i-512)/8, 512+(i-512)%8]
// ---------------------------------------------------------------------------
__global__ __launch_bounds__(256)
void mix1_kernel(const float* __restrict__ X, const float* __restrict__ Omega,
                 unsigned short* __restrict__ xt1)
{
  const int idx = blockIdx.x * 256 + threadIdx.x;      // 256*992 total
  const int b = idx / MOE_IN_N;
  const int i = idx - b * MOE_IN_N;
  const float* Xb = X + (size_t)b * (T_N * IN_N);
  float xm;
  if (i < MOE_RAW_N) {
    xm = Xb[(T_N - 1) * IN_N + i];
  } else {
    const int t = (i - MOE_RAW_N) >> 3, g = (i - MOE_RAW_N) & 7;
    xm = Xb[t * IN_N + MOE_RAW_N + g];
  }
  const int swz = (b & 7) << 3;
  unsigned short* row = xt1 + (size_t)b * K1_N;
#pragma unroll
  for (int e = 0; e < 8; ++e) {
    float w = Omega[b * 8 + e];
    row[(e * MOE_IN_N + i) ^ swz] = f2bf(w * xm);
  }
}

// ---------------------------------------------------------------------------
// Split-K GEMM: P[sp][256][NPAD] += A(bf16, swizzled [256][K]) * Bw(fp32 [K][N])
// BM=256 (full M), BN=64, BK=64, 4 waves, wave = 64 rows x 64 cols.
// A staged via global_load_lds (16B), B reg-staged fp32->bf16, transposed,
// XOR-swizzled LDS ( chunk ^= row&7 within 128B rows ).
// ---------------------------------------------------------------------------
__global__ __launch_bounds__(256)
void gemm_splitk(const unsigned short* __restrict__ A,
                 const float* __restrict__ Bw,
                 float* __restrict__ P,
                 int K, int N, int NPAD)
{
  __shared__ unsigned short Al[2][256][64];   // 64 KB
  __shared__ unsigned short Bl[2][64][64];    // 16 KB  (Bl[n][k], transposed)

  const int tid = threadIdx.x;
  const int lane = tid & 63;
  const int wave = tid >> 6;
  const int nt = blockIdx.x, sp = blockIdx.y;
  const int n0 = nt * 64;
  const int KT = K >> 6;
  const int kt0 = (KT * sp) / SPLITK;
  const int kt1 = (KT * (sp + 1)) / SPLITK;

  const int r15 = lane & 15, hi4 = lane >> 4, r7 = lane & 7;

  // A staging: each wave stages its own 64 rows, 8 gload_lds per K-tile
  const unsigned short* Abase = A + (size_t)(wave * 64 + (lane >> 3)) * K + (lane & 7) * 8;
  // B staging: thread t -> col n=t&63, k-quarter kq=t>>6 (16 consecutive k)
  const int bn = lane;
  const int kq = wave;
  const bool nvalid = (n0 + bn) < N;
  const float* Bbase = Bw + (size_t)(kq * 16) * N + (n0 + bn);

  f32x4 acc[4][4];
  const f32x4 zero4 = {0.f, 0.f, 0.f, 0.f};
#pragma unroll
  for (int mi = 0; mi < 4; ++mi)
#pragma unroll
    for (int ni = 0; ni < 4; ++ni) acc[mi][ni] = zero4;

  auto stage = [&](int bufi, int kt) {
    const unsigned short* ga = Abase + kt * 64;
#pragma unroll
    for (int it = 0; it < 8; ++it) {
      __builtin_amdgcn_global_load_lds(
          (AS1Q unsigned int*)(ga + (size_t)it * 8 * K),
          (AS3Q unsigned int*)&Al[bufi][wave * 64 + it * 8][0],
          16, 0, 0);
    }
    const float* gb = Bbase + (size_t)kt * 64 * N;
    float v[16];
#pragma unroll
    for (int jj = 0; jj < 16; ++jj) v[jj] = nvalid ? gb[(size_t)jj * N] : 0.f;
    ushort8 p0, p1;
#pragma unroll
    for (int jj = 0; jj < 8; ++jj) { p0[jj] = f2bf(v[jj]); p1[jj] = f2bf(v[jj + 8]); }
    const int sl0 = ((kq * 2) ^ (bn & 7)) * 8;       // 8-elem (16B) chunk slots
    const int sl1 = ((kq * 2 + 1) ^ (bn & 7)) * 8;
    *(ushort8*)&Bl[bufi][bn][sl0] = p0;
    *(ushort8*)&Bl[bufi][bn][sl1] = p1;
  };

  auto compute = [&](int bufi) {
#pragma unroll
    for (int ki = 0; ki < 2; ++ki) {
      const int ch = ((ki * 4 + hi4) ^ r7) * 8;      // un-swizzle on read
      short8 af[4], bfv[4];
#pragma unroll
      for (int mi = 0; mi < 4; ++mi)
        af[mi] = *(const short8*)&Al[bufi][wave * 64 + mi * 16 + r15][ch];
#pragma unroll
      for (int ni = 0; ni < 4; ++ni)
        bfv[ni] = *(const short8*)&Bl[bufi][ni * 16 + r15][ch];
#pragma unroll
      for (int mi = 0; mi < 4; ++mi)
#pragma unroll
        for (int ni = 0; ni < 4; ++ni)
          acc[mi][ni] = __builtin_amdgcn_mfma_f32_16x16x32_bf16(af[mi], bfv[ni], acc[mi][ni], 0, 0, 0);
    }
  };

  stage(0, kt0);
  __syncthreads();
  int buf = 0;
  for (int kt = kt0; kt < kt1; ++kt) {
    if (kt + 1 < kt1) stage(buf ^ 1, kt + 1);
    compute(buf);
    __syncthreads();
    buf ^= 1;
  }

  // C/D layout: col = lane&15, row = (lane>>4)*4 + rr   [m89-verified]
  float* Pp = P + (size_t)sp * 256 * NPAD + n0;
#pragma unroll
  for (int mi = 0; mi < 4; ++mi) {
    const int row = wave * 64 + mi * 16 + hi4 * 4;
#pragma unroll
    for (int ni = 0; ni < 4; ++ni) {
#pragma unroll
      for (int rr = 0; rr < 4; ++rr)
        Pp[(size_t)(row + rr) * NPAD + ni * 16 + r15] = acc[mi][ni][rr];
    }
  }
}

// ---------------------------------------------------------------------------
// Reduce split-K partials + Omega-blended bias; then either
//  - ELU + write swizzled bf16 mixed input for next layer (xnext != nullptr)
//  - or write final fp32 output (Yout != nullptr)
// ---------------------------------------------------------------------------
__global__ __launch_bounds__(256)
void reduce_mix_kernel(const float* __restrict__ P, const float* __restrict__ Omega,
                       const float* __restrict__ bias, unsigned short* __restrict__ xnext,
                       float* __restrict__ Yout, int N, int NPAD)
{
  const int n = blockIdx.x * 256 + threadIdx.x;
  const int b = blockIdx.y;
  if (n >= N) return;
  float acc = 0.f;
#pragma unroll 4
  for (int s = 0; s < SPLITK; ++s) acc += P[((size_t)s * 256 + b) * NPAD + n];
  float om[8];
#pragma unroll
  for (int e = 0; e < 8; ++e) om[e] = Omega[b * 8 + e];
  float bs = 0.f;
#pragma unroll
  for (int e = 0; e < 8; ++e) bs += om[e] * bias[(size_t)e * N + n];
  float y = acc + bs;
  if (Yout) { Yout[(size_t)b * N + n] = y; return; }
  float a = (y > 0.f) ? y : expm1f(y);            // ELU
  const int swz = (b & 7) << 3;
  unsigned short* row = xnext + (size_t)b * K2_N;
#pragma unroll
  for (int e = 0; e < 8; ++e)
    row[(e * HID_N + n) ^ swz] = f2bf(om[e] * a);
}

// ---------------------------------------------------------------------------
extern "C" void kernel_launch(void* const* d_in, const int* in_sizes, int n_in,
                              void* d_out, int out_size, void* d_ws, size_t ws_size,
                              hipStream_t stream) {
  const float* X    = (const float*)d_in[0];
  const float* Wih0 = (const float*)d_in[1];
  const float* Whh0 = (const float*)d_in[2];
  const float* bih0 = (const float*)d_in[3];
  const float* bhh0 = (const float*)d_in[4];
  const float* Wih1 = (const float*)d_in[5];
  const float* Whh1 = (const float*)d_in[6];
  const float* bih1 = (const float*)d_in[7];
  const float* bhh1 = (const float*)d_in[8];
  const float* w1   = (const float*)d_in[9];
  const float* b1   = (const float*)d_in[10];
  const float* w2   = (const float*)d_in[11];
  const float* b2   = (const float*)d_in[12];
  const float* w3   = (const float*)d_in[13];
  const float* b3   = (const float*)d_in[14];

  char* ws = (char*)d_ws;
  float* Omega        = (float*)ws;                                  // 8 KB
  unsigned short* xt1 = (unsigned short*)(ws + 8192);                // 256*7936*2 = 4,063,232
  unsigned short* xt2 = (unsigned short*)(ws + 8192 + 4063232);      // 256*6016*2 = 3,080,192
  unsigned short* xt3 = (unsigned short*)(ws + 8192 + 4063232 + 3080192);
  float* P            = (float*)(ws + 8192 + 4063232 + 3080192 + 3080192); // 20*256*768*4 = 15,728,640

  gru_omega_kernel<<<32, 64, 0, stream>>>(X, Wih0, Whh0, bih0, bhh0,
                                          Wih1, Whh1, bih1, bhh1, Omega);
  mix1_kernel<<<992, 256, 0, stream>>>(X, Omega, xt1);

  // layer 1: 256 x 7936 @ 7936 x 752
  gemm_splitk<<<dim3(12, SPLITK), 256, 0, stream>>>(xt1, w1, P, K1_N, HID_N, 768);
  reduce_mix_kernel<<<dim3(3, 256), 256, 0, stream>>>(P, Omega, b1, xt2, nullptr, HID_N, 768);

  // layer 2: 256 x 6016 @ 6016 x 752
  gemm_splitk<<<dim3(12, SPLITK), 256, 0, stream>>>(xt2, w2, P, K2_N, HID_N, 768);
  reduce_mix_kernel<<<dim3(3, 256), 256, 0, stream>>>(P, Omega, b2, xt3, nullptr, HID_N, 768);

  // layer 3: 256 x 6016 @ 6016 x 512
  gemm_splitk<<<dim3(8, SPLITK), 256, 0, stream>>>(xt3, w3, P, K2_N, 512, 512);
  reduce_mix_kernel<<<dim3(2, 256), 256, 0, stream>>>(P, Omega, b3, nullptr, (float*)d_out, 512, 512);
}

// Round 3
// 101.902 us; speedup vs baseline: 1.0949x; 1.0235x over previous
//
#include <hip/hip_runtime.h>
#include <cstdint>
#include <cstddef>

typedef __attribute__((ext_vector_type(8))) short short8;
typedef __attribute__((ext_vector_type(8))) unsigned short ushort8;
typedef __attribute__((ext_vector_type(4))) float f32x4;

#define AS1Q const __attribute__((address_space(1)))
#define AS3Q __attribute__((address_space(3)))

constexpr int T_N = 60, IN_N = 520, MOE_RAW_N = 512, MOE_IN_N = 992;
constexpr int HID_N = 752, E_N = 8;
constexpr int K1_N = 7936, K2_N = 6016;   // 8*992, 8*752
constexpr int SPLITK = 20;

static __device__ __forceinline__ unsigned short f2bf(float f) {
  unsigned int u = __float_as_uint(f);
  return (unsigned short)((u + 0x7fffu + ((u >> 16) & 1u)) >> 16);   // RNE
}
static __device__ __forceinline__ float sigf(float x) {
  return __fdividef(1.f, 1.f + __expf(-x));
}
static __device__ __forceinline__ float tanh_fast(float x) {
  return 2.f * __fdividef(1.f, 1.f + __expf(-2.f * x)) - 1.f;
}

// ---------------------------------------------------------------------------
// GRU (2 layers, H=8) -> Omega = softmax(h2[:, -1, :]).
// 8 lanes per sample (one per hidden unit), 8 samples per wave, 1 wave/block.
// X gate slice staged in LDS (parallel pre-pass) -> the 60-step serial chain
// contains only LDS reads (static addrs), 16 bpermutes, FMAs, trans ops.
// __launch_bounds__(64,1): allow a large VGPR budget -> NO scratch spill
// (round-2 failure mode: VGPR capped at 104, weights+x spilled to scratch,
// FETCH_SIZE grew 0.6 MB and the chain ate scratch latency every step).
// ---------------------------------------------------------------------------
__global__ __launch_bounds__(64, 1)
void gru_omega_kernel(const float* __restrict__ X,
                      const float* __restrict__ Wih0, const float* __restrict__ Whh0,
                      const float* __restrict__ bih0, const float* __restrict__ bhh0,
                      const float* __restrict__ Wih1, const float* __restrict__ Whh1,
                      const float* __restrict__ bih1, const float* __restrict__ bhh1,
                      float* __restrict__ Omega)
{
  __shared__ float xl[8][T_N][8];   // 15 KB

  const int lane = threadIdx.x;
  const int j = lane & 7;          // hidden unit
  const int base = lane & 56;      // 8-lane group base
  const int s = lane >> 3;         // sample within block
  const int b = blockIdx.x * 8 + s;

  // ---- parallel pre-pass: stage gate-input slice into LDS ----
  const float* xb = X + (size_t)b * (T_N * IN_N) + MOE_RAW_N;
#pragma unroll
  for (int t = 0; t < T_N; ++t) xl[s][t][j] = xb[t * IN_N + j];

  float wi0r[8], wi0z[8], wi0n[8], wh0r[8], wh0z[8], wh0n[8];
  float wi1r[8], wi1z[8], wi1n[8], wh1r[8], wh1z[8], wh1n[8];
#pragma unroll
  for (int i = 0; i < 8; ++i) {
    wi0r[i] = Wih0[j * 8 + i]; wi0z[i] = Wih0[(8 + j) * 8 + i]; wi0n[i] = Wih0[(16 + j) * 8 + i];
    wh0r[i] = Whh0[j * 8 + i]; wh0z[i] = Whh0[(8 + j) * 8 + i]; wh0n[i] = Whh0[(16 + j) * 8 + i];
    wi1r[i] = Wih1[j * 8 + i]; wi1z[i] = Wih1[(8 + j) * 8 + i]; wi1n[i] = Wih1[(16 + j) * 8 + i];
    wh1r[i] = Whh1[j * 8 + i]; wh1z[i] = Whh1[(8 + j) * 8 + i]; wh1n[i] = Whh1[(16 + j) * 8 + i];
  }
  const float br0 = bih0[j] + bhh0[j], bz0 = bih0[8 + j] + bhh0[8 + j];
  const float bin0 = bih0[16 + j],     bhn0 = bhh0[16 + j];
  const float br1 = bih1[j] + bhh1[j], bz1 = bih1[8 + j] + bhh1[8 + j];
  const float bin1 = bih1[16 + j],     bhn1 = bhh1[16 + j];

  __syncthreads();   // 1 wave/block: compiles to a cheap lgkmcnt fence

  float h1 = 0.f, h2 = 0.f;
  float bh1[8], bh2[8];            // cached broadcasts of h1(t) / h2(t)
#pragma unroll
  for (int i = 0; i < 8; ++i) { bh1[i] = 0.f; bh2[i] = 0.f; }

#pragma unroll
  for (int t = 0; t < T_N; ++t) {
    const f32x4 x0 = *(const f32x4*)&xl[s][t][0];
    const f32x4 x1 = *(const f32x4*)&xl[s][t][4];

    // ---- layer 0: uses x(t) and bh1 = broadcasts of h1(t-1) ----
    float gr = br0, gz = bz0, gn = bin0, hn = bhn0;
#pragma unroll
    for (int i = 0; i < 4; ++i) {
      gr += wi0r[i] * x0[i]; gz += wi0z[i] * x0[i]; gn += wi0n[i] * x0[i];
      gr += wi0r[4 + i] * x1[i]; gz += wi0z[4 + i] * x1[i]; gn += wi0n[4 + i] * x1[i];
    }
#pragma unroll
    for (int i = 0; i < 8; ++i) {
      gr += wh0r[i] * bh1[i]; gz += wh0z[i] * bh1[i]; hn += wh0n[i] * bh1[i];
    }
    float r = sigf(gr), z = sigf(gz);
    float n = tanh_fast(gn + r * hn);
    h1 = (1.f - z) * n + z * h1;

    // broadcast h1(t): used by layer 1 now AND layer 0 next step
#pragma unroll
    for (int i = 0; i < 8; ++i) bh1[i] = __shfl(h1, base + i);

    // ---- layer 1: uses bh1 = h1(t) and bh2 = broadcasts of h2(t-1) ----
    gr = br1; gz = bz1; gn = bin1; hn = bhn1;
#pragma unroll
    for (int i = 0; i < 8; ++i) {
      gr += wi1r[i] * bh1[i]; gz += wi1z[i] * bh1[i]; gn += wi1n[i] * bh1[i];
    }
#pragma unroll
    for (int i = 0; i < 8; ++i) {
      gr += wh1r[i] * bh2[i]; gz += wh1z[i] * bh2[i]; hn += wh1n[i] * bh2[i];
    }
    r = sigf(gr); z = sigf(gz);
    n = tanh_fast(gn + r * hn);
    h2 = (1.f - z) * n + z * h2;

    // broadcast h2(t): only needed by layer 1 next step (off critical path)
#pragma unroll
    for (int i = 0; i < 8; ++i) bh2[i] = __shfl(h2, base + i);
  }

  // softmax over the 8-lane group
  float m = h2;
#pragma unroll
  for (int d = 1; d < 8; d <<= 1) m = fmaxf(m, __shfl_xor(m, d));
  float e = __expf(h2 - m);
  float sden = e;
#pragma unroll
  for (int d = 1; d < 8; d <<= 1) sden += __shfl_xor(sden, d);
  Omega[b * 8 + j] = __fdividef(e, sden);
}

// ---------------------------------------------------------------------------
// Build x~1[b, (e*992+i) ^ swz] = bf16(Omega[b,e] * Xm[b,i])  (swizzled bf16)
// Xm[b,i] = X[b,59,i] (i<512) else X[b,(i-512)/8, 512+(i-512)%8]
// ---------------------------------------------------------------------------
__global__ __launch_bounds__(256)
void mix1_kernel(const float* __restrict__ X, const float* __restrict__ Omega,
                 unsigned short* __restrict__ xt1)
{
  const int idx = blockIdx.x * 256 + threadIdx.x;      // 256*992 total
  const int b = idx / MOE_IN_N;
  const int i = idx - b * MOE_IN_N;
  const float* Xb = X + (size_t)b * (T_N * IN_N);
  float xm;
  if (i < MOE_RAW_N) {
    xm = Xb[(T_N - 1) * IN_N + i];
  } else {
    const int t = (i - MOE_RAW_N) >> 3, g = (i - MOE_RAW_N) & 7;
    xm = Xb[t * IN_N + MOE_RAW_N + g];
  }
  const int swz = (b & 7) << 3;
  unsigned short* row = xt1 + (size_t)b * K1_N;
#pragma unroll
  for (int e = 0; e < 8; ++e) {
    float w = Omega[b * 8 + e];
    row[(e * MOE_IN_N + i) ^ swz] = f2bf(w * xm);
  }
}

// ---------------------------------------------------------------------------
// Split-K GEMM: P[sp][256][NPAD] += A(bf16, swizzled [256][K]) * Bw(fp32 [K][N])
// BM=256 (full M), BN=64, BK=64, 4 waves, wave = 64 rows x 64 cols.
// A staged via global_load_lds (16B), B reg-staged fp32->bf16, transposed,
// XOR-swizzled LDS ( chunk ^= row&7 within 128B rows ).
// ---------------------------------------------------------------------------
__global__ __launch_bounds__(256)
void gemm_splitk(const unsigned short* __restrict__ A,
                 const float* __restrict__ Bw,
                 float* __restrict__ P,
                 int K, int N, int NPAD)
{
  __shared__ unsigned short Al[2][256][64];   // 64 KB
  __shared__ unsigned short Bl[2][64][64];    // 16 KB  (Bl[n][k], transposed)

  const int tid = threadIdx.x;
  const int lane = tid & 63;
  const int wave = tid >> 6;
  const int nt = blockIdx.x, sp = blockIdx.y;
  const int n0 = nt * 64;
  const int KT = K >> 6;
  const int kt0 = (KT * sp) / SPLITK;
  const int kt1 = (KT * (sp + 1)) / SPLITK;

  const int r15 = lane & 15, hi4 = lane >> 4, r7 = lane & 7;

  // A staging: each wave stages its own 64 rows, 8 gload_lds per K-tile
  const unsigned short* Abase = A + (size_t)(wave * 64 + (lane >> 3)) * K + (lane & 7) * 8;
  // B staging: thread t -> col n=t&63, k-quarter kq=t>>6 (16 consecutive k)
  const int bn = lane;
  const int kq = wave;
  const bool nvalid = (n0 + bn) < N;
  const float* Bbase = Bw + (size_t)(kq * 16) * N + (n0 + bn);

  f32x4 acc[4][4];
  const f32x4 zero4 = {0.f, 0.f, 0.f, 0.f};
#pragma unroll
  for (int mi = 0; mi < 4; ++mi)
#pragma unroll
    for (int ni = 0; ni < 4; ++ni) acc[mi][ni] = zero4;

  auto stage = [&](int bufi, int kt) {
    const unsigned short* ga = Abase + kt * 64;
#pragma unroll
    for (int it = 0; it < 8; ++it) {
      __builtin_amdgcn_global_load_lds(
          (AS1Q unsigned int*)(ga + (size_t)it * 8 * K),
          (AS3Q unsigned int*)&Al[bufi][wave * 64 + it * 8][0],
          16, 0, 0);
    }
    const float* gb = Bbase + (size_t)kt * 64 * N;
    float v[16];
#pragma unroll
    for (int jj = 0; jj < 16; ++jj) v[jj] = nvalid ? gb[(size_t)jj * N] : 0.f;
    ushort8 p0, p1;
#pragma unroll
    for (int jj = 0; jj < 8; ++jj) { p0[jj] = f2bf(v[jj]); p1[jj] = f2bf(v[jj + 8]); }
    const int sl0 = ((kq * 2) ^ (bn & 7)) * 8;       // 8-elem (16B) chunk slots
    const int sl1 = ((kq * 2 + 1) ^ (bn & 7)) * 8;
    *(ushort8*)&Bl[bufi][bn][sl0] = p0;
    *(ushort8*)&Bl[bufi][bn][sl1] = p1;
  };

  auto compute = [&](int bufi) {
#pragma unroll
    for (int ki = 0; ki < 2; ++ki) {
      const int ch = ((ki * 4 + hi4) ^ r7) * 8;      // un-swizzle on read
      short8 af[4], bfv[4];
#pragma unroll
      for (int mi = 0; mi < 4; ++mi)
        af[mi] = *(const short8*)&Al[bufi][wave * 64 + mi * 16 + r15][ch];
#pragma unroll
      for (int ni = 0; ni < 4; ++ni)
        bfv[ni] = *(const short8*)&Bl[bufi][ni * 16 + r15][ch];
#pragma unroll
      for (int mi = 0; mi < 4; ++mi)
#pragma unroll
        for (int ni = 0; ni < 4; ++ni)
          acc[mi][ni] = __builtin_amdgcn_mfma_f32_16x16x32_bf16(af[mi], bfv[ni], acc[mi][ni], 0, 0, 0);
    }
  };

  stage(0, kt0);
  __syncthreads();
  int buf = 0;
  for (int kt = kt0; kt < kt1; ++kt) {
    if (kt + 1 < kt1) stage(buf ^ 1, kt + 1);
    compute(buf);
    __syncthreads();
    buf ^= 1;
  }

  // C/D layout: col = lane&15, row = (lane>>4)*4 + rr   [m89-verified]
  float* Pp = P + (size_t)sp * 256 * NPAD + n0;
#pragma unroll
  for (int mi = 0; mi < 4; ++mi) {
    const int row = wave * 64 + mi * 16 + hi4 * 4;
#pragma unroll
    for (int ni = 0; ni < 4; ++ni) {
#pragma unroll
      for (int rr = 0; rr < 4; ++rr)
        Pp[(size_t)(row + rr) * NPAD + ni * 16 + r15] = acc[mi][ni][rr];
    }
  }
}

// ---------------------------------------------------------------------------
// Reduce split-K partials + Omega-blended bias; then either
//  - ELU + write swizzled bf16 mixed input for next layer (xnext != nullptr)
//  - or write final fp32 output (Yout != nullptr)
// ---------------------------------------------------------------------------
__global__ __launch_bounds__(256)
void reduce_mix_kernel(const float* __restrict__ P, const float* __restrict__ Omega,
                       const float* __restrict__ bias, unsigned short* __restrict__ xnext,
                       float* __restrict__ Yout, int N, int NPAD)
{
  const int n = blockIdx.x * 256 + threadIdx.x;
  const int b = blockIdx.y;
  if (n >= N) return;
  float acc = 0.f;
#pragma unroll 4
  for (int s = 0; s < SPLITK; ++s) acc += P[((size_t)s * 256 + b) * NPAD + n];
  float om[8];
#pragma unroll
  for (int e = 0; e < 8; ++e) om[e] = Omega[b * 8 + e];
  float bs = 0.f;
#pragma unroll
  for (int e = 0; e < 8; ++e) bs += om[e] * bias[(size_t)e * N + n];
  float y = acc + bs;
  if (Yout) { Yout[(size_t)b * N + n] = y; return; }
  float a = (y > 0.f) ? y : expm1f(y);            // ELU
  const int swz = (b & 7) << 3;
  unsigned short* row = xnext + (size_t)b * K2_N;
#pragma unroll
  for (int e = 0; e < 8; ++e)
    row[(e * HID_N + n) ^ swz] = f2bf(om[e] * a);
}

// ---------------------------------------------------------------------------
extern "C" void kernel_launch(void* const* d_in, const int* in_sizes, int n_in,
                              void* d_out, int out_size, void* d_ws, size_t ws_size,
                              hipStream_t stream) {
  const float* X    = (const float*)d_in[0];
  const float* Wih0 = (const float*)d_in[1];
  const float* Whh0 = (const float*)d_in[2];
  const float* bih0 = (const float*)d_in[3];
  const float* bhh0 = (const float*)d_in[4];
  const float* Wih1 = (const float*)d_in[5];
  const float* Whh1 = (const float*)d_in[6];
  const float* bih1 = (const float*)d_in[7];
  const float* bhh1 = (const float*)d_in[8];
  const float* w1   = (const float*)d_in[9];
  const float* b1   = (const float*)d_in[10];
  const float* w2   = (const float*)d_in[11];
  const float* b2   = (const float*)d_in[12];
  const float* w3   = (const float*)d_in[13];
  const float* b3   = (const float*)d_in[14];

  char* ws = (char*)d_ws;
  float* Omega        = (float*)ws;                                  // 8 KB
  unsigned short* xt1 = (unsigned short*)(ws + 8192);                // 256*7936*2 = 4,063,232
  unsigned short* xt2 = (unsigned short*)(ws + 8192 + 4063232);      // 256*6016*2 = 3,080,192
  unsigned short* xt3 = (unsigned short*)(ws + 8192 + 4063232 + 3080192);
  float* P            = (float*)(ws + 8192 + 4063232 + 3080192 + 3080192); // 20*256*768*4 = 15,728,640

  gru_omega_kernel<<<32, 64, 0, stream>>>(X, Wih0, Whh0, bih0, bhh0,
                                          Wih1, Whh1, bih1, bhh1, Omega);
  mix1_kernel<<<992, 256, 0, stream>>>(X, Omega, xt1);

  // layer 1: 256 x 7936 @ 7936 x 752
  gemm_splitk<<<dim3(12, SPLITK), 256, 0, stream>>>(xt1, w1, P, K1_N, HID_N, 768);
  reduce_mix_kernel<<<dim3(3, 256), 256, 0, stream>>>(P, Omega, b1, xt2, nullptr, HID_N, 768);

  // layer 2: 256 x 6016 @ 6016 x 752
  gemm_splitk<<<dim3(12, SPLITK), 256, 0, stream>>>(xt2, w2, P, K2_N, HID_N, 768);
  reduce_mix_kernel<<<dim3(3, 256), 256, 0, stream>>>(P, Omega, b2, xt3, nullptr, HID_N, 768);

  // layer 3: 256 x 6016 @ 6016 x 512
  gemm_splitk<<<dim3(8, SPLITK), 256, 0, stream>>>(xt3, w3, P, K2_N, 512, 512);
  reduce_mix_kernel<<<dim3(2, 256), 256, 0, stream>>>(P, Omega, b3, nullptr, (float*)d_out, 512, 512);
}

// Round 4
// 97.970 us; speedup vs baseline: 1.1388x; 1.0401x over previous
//
#include <hip/hip_runtime.h>
#include <cstdint>
#include <cstddef>

typedef __attribute__((ext_vector_type(8))) short short8;
typedef __attribute__((ext_vector_type(8))) unsigned short ushort8;
typedef __attribute__((ext_vector_type(4))) float f32x4;

#define AS1Q const __attribute__((address_space(1)))
#define AS3Q __attribute__((address_space(3)))

constexpr int T_N = 60, IN_N = 520, MOE_RAW_N = 512, MOE_IN_N = 992;
constexpr int HID_N = 752, E_N = 8;
constexpr int K1_N = 7936, K2_N = 6016;   // 8*992, 8*752
constexpr int SPLITK = 20;

static __device__ __forceinline__ unsigned short f2bf(float f) {
  unsigned int u = __float_as_uint(f);
  return (unsigned short)((u + 0x7fffu + ((u >> 16) & 1u)) >> 16);   // RNE
}
static __device__ __forceinline__ float sigf(float x) {
  return __fdividef(1.f, 1.f + __expf(-x));
}
static __device__ __forceinline__ float tanh_fast(float x) {
  return 2.f * __fdividef(1.f, 1.f + __expf(-2.f * x)) - 1.f;
}

// ---------------------------------------------------------------------------
// GRU (2 layers, H=8) -> Omega = softmax(h2[:, -1, :]).
// 8 lanes per sample, 8 samples per wave, 1 wave per block.
// ROUND-4 FIX: the serial t-loop is NOT unrolled (#pragma unroll 1).
// Rounds 1-3 fully unrolled it -> ~80KB straight-line code > 32KB L1I ->
// every instruction a cold I-fetch (VALUBusy ~10% on active CUs, FETCH_SIZE
// carried ~0.6MB of code traffic). Body is ~1KB now and fits L1I after the
// first iteration. X gate slice staged via global_load_lds into lane-linear
// LDS layout xl[t][s][j] (lane = s*8+j -> dest base + lane*4).
// ---------------------------------------------------------------------------
__global__ __launch_bounds__(64, 1)
void gru_omega_kernel(const float* __restrict__ X,
                      const float* __restrict__ Wih0, const float* __restrict__ Whh0,
                      const float* __restrict__ bih0, const float* __restrict__ bhh0,
                      const float* __restrict__ Wih1, const float* __restrict__ Whh1,
                      const float* __restrict__ bih1, const float* __restrict__ bhh1,
                      float* __restrict__ Omega)
{
  __shared__ float xl[T_N][8][8];   // 15 KB, [t][sample][j] — lane-linear per t

  const int lane = threadIdx.x;
  const int j = lane & 7;          // hidden unit
  const int base = lane & 56;      // 8-lane group base
  const int s = lane >> 3;         // sample within block
  const int b = blockIdx.x * 8 + s;

  // ---- stage gate-input slice: 60 x global_load_lds (width 4) ----
  const float* xsrc = X + (size_t)b * (T_N * IN_N) + MOE_RAW_N + j;
#pragma unroll
  for (int t = 0; t < T_N; ++t) {
    __builtin_amdgcn_global_load_lds((AS1Q unsigned int*)(xsrc + t * IN_N),
                                     (AS3Q unsigned int*)&xl[t][0][0], 4, 0, 0);
  }

  float wi0r[8], wi0z[8], wi0n[8], wh0r[8], wh0z[8], wh0n[8];
  float wi1r[8], wi1z[8], wi1n[8], wh1r[8], wh1z[8], wh1n[8];
#pragma unroll
  for (int i = 0; i < 8; ++i) {
    wi0r[i] = Wih0[j * 8 + i]; wi0z[i] = Wih0[(8 + j) * 8 + i]; wi0n[i] = Wih0[(16 + j) * 8 + i];
    wh0r[i] = Whh0[j * 8 + i]; wh0z[i] = Whh0[(8 + j) * 8 + i]; wh0n[i] = Whh0[(16 + j) * 8 + i];
    wi1r[i] = Wih1[j * 8 + i]; wi1z[i] = Wih1[(8 + j) * 8 + i]; wi1n[i] = Wih1[(16 + j) * 8 + i];
    wh1r[i] = Whh1[j * 8 + i]; wh1z[i] = Whh1[(8 + j) * 8 + i]; wh1n[i] = Whh1[(16 + j) * 8 + i];
  }
  const float br0 = bih0[j] + bhh0[j], bz0 = bih0[8 + j] + bhh0[8 + j];
  const float bin0 = bih0[16 + j],     bhn0 = bhh0[16 + j];
  const float br1 = bih1[j] + bhh1[j], bz1 = bih1[8 + j] + bhh1[8 + j];
  const float bin1 = bih1[16 + j],     bhn1 = bhh1[16 + j];

  __syncthreads();   // single wave: drains vmcnt for the global_load_lds

  float h1 = 0.f, h2 = 0.f;
  float bh1[8], bh2[8];            // cached broadcasts of h1(t) / h2(t)
#pragma unroll
  for (int i = 0; i < 8; ++i) { bh1[i] = 0.f; bh2[i] = 0.f; }

#pragma unroll 1                    // keep body ~1KB: MUST fit L1I
  for (int t = 0; t < T_N; ++t) {
    const f32x4 x0 = *(const f32x4*)&xl[t][s][0];
    const f32x4 x1 = *(const f32x4*)&xl[t][s][4];

    // ---- layer 0: x(t) and bh1 = broadcasts of h1(t-1) ----
    float gr = br0, gz = bz0, gn = bin0, hn = bhn0;
#pragma unroll
    for (int i = 0; i < 4; ++i) {
      gr += wi0r[i] * x0[i]; gz += wi0z[i] * x0[i]; gn += wi0n[i] * x0[i];
      gr += wi0r[4 + i] * x1[i]; gz += wi0z[4 + i] * x1[i]; gn += wi0n[4 + i] * x1[i];
    }
#pragma unroll
    for (int i = 0; i < 8; ++i) {
      gr += wh0r[i] * bh1[i]; gz += wh0z[i] * bh1[i]; hn += wh0n[i] * bh1[i];
    }
    float r = sigf(gr), z = sigf(gz);
    float n = tanh_fast(gn + r * hn);
    h1 = (1.f - z) * n + z * h1;

    // broadcast h1(t): used by layer 1 now AND layer 0 next step
#pragma unroll
    for (int i = 0; i < 8; ++i) bh1[i] = __shfl(h1, base + i);

    // ---- layer 1: bh1 = h1(t), bh2 = broadcasts of h2(t-1) ----
    gr = br1; gz = bz1; gn = bin1; hn = bhn1;
#pragma unroll
    for (int i = 0; i < 8; ++i) {
      gr += wi1r[i] * bh1[i]; gz += wi1z[i] * bh1[i]; gn += wi1n[i] * bh1[i];
    }
#pragma unroll
    for (int i = 0; i < 8; ++i) {
      gr += wh1r[i] * bh2[i]; gz += wh1z[i] * bh2[i]; hn += wh1n[i] * bh2[i];
    }
    r = sigf(gr); z = sigf(gz);
    n = tanh_fast(gn + r * hn);
    h2 = (1.f - z) * n + z * h2;

    // broadcast h2(t): only needed next step (off critical path)
#pragma unroll
    for (int i = 0; i < 8; ++i) bh2[i] = __shfl(h2, base + i);
  }

  // softmax over the 8-lane group
  float m = h2;
#pragma unroll
  for (int d = 1; d < 8; d <<= 1) m = fmaxf(m, __shfl_xor(m, d));
  float e = __expf(h2 - m);
  float sden = e;
#pragma unroll
  for (int d = 1; d < 8; d <<= 1) sden += __shfl_xor(sden, d);
  Omega[b * 8 + j] = __fdividef(e, sden);
}

// ---------------------------------------------------------------------------
// Build x~1[b, (e*992+i) ^ swz] = bf16(Omega[b,e] * Xm[b,i])  (swizzled bf16)
// Xm[b,i] = X[b,59,i] (i<512) else X[b,(i-512)/8, 512+(i-512)%8]
// ---------------------------------------------------------------------------
__global__ __launch_bounds__(256)
void mix1_kernel(const float* __restrict__ X, const float* __restrict__ Omega,
                 unsigned short* __restrict__ xt1)
{
  const int idx = blockIdx.x * 256 + threadIdx.x;      // 256*992 total
  const int b = idx / MOE_IN_N;
  const int i = idx - b * MOE_IN_N;
  const float* Xb = X + (size_t)b * (T_N * IN_N);
  float xm;
  if (i < MOE_RAW_N) {
    xm = Xb[(T_N - 1) * IN_N + i];
  } else {
    const int t = (i - MOE_RAW_N) >> 3, g = (i - MOE_RAW_N) & 7;
    xm = Xb[t * IN_N + MOE_RAW_N + g];
  }
  const int swz = (b & 7) << 3;
  unsigned short* row = xt1 + (size_t)b * K1_N;
#pragma unroll
  for (int e = 0; e < 8; ++e) {
    float w = Omega[b * 8 + e];
    row[(e * MOE_IN_N + i) ^ swz] = f2bf(w * xm);
  }
}

// ---------------------------------------------------------------------------
// Split-K GEMM: P[sp][256][NPAD] += A(bf16, swizzled [256][K]) * Bw(fp32 [K][N])
// BM=256 (full M), BN=64, BK=64, 4 waves, wave = 64 rows x 64 cols.
// A staged via global_load_lds (16B), B reg-staged fp32->bf16, transposed,
// XOR-swizzled LDS ( chunk ^= row&7 within 128B rows ).
// ---------------------------------------------------------------------------
__global__ __launch_bounds__(256)
void gemm_splitk(const unsigned short* __restrict__ A,
                 const float* __restrict__ Bw,
                 float* __restrict__ P,
                 int K, int N, int NPAD)
{
  __shared__ unsigned short Al[2][256][64];   // 64 KB
  __shared__ unsigned short Bl[2][64][64];    // 16 KB  (Bl[n][k], transposed)

  const int tid = threadIdx.x;
  const int lane = tid & 63;
  const int wave = tid >> 6;
  const int nt = blockIdx.x, sp = blockIdx.y;
  const int n0 = nt * 64;
  const int KT = K >> 6;
  const int kt0 = (KT * sp) / SPLITK;
  const int kt1 = (KT * (sp + 1)) / SPLITK;

  const int r15 = lane & 15, hi4 = lane >> 4, r7 = lane & 7;

  // A staging: each wave stages its own 64 rows, 8 gload_lds per K-tile
  const unsigned short* Abase = A + (size_t)(wave * 64 + (lane >> 3)) * K + (lane & 7) * 8;
  // B staging: thread t -> col n=t&63, k-quarter kq=t>>6 (16 consecutive k)
  const int bn = lane;
  const int kq = wave;
  const bool nvalid = (n0 + bn) < N;
  const float* Bbase = Bw + (size_t)(kq * 16) * N + (n0 + bn);

  f32x4 acc[4][4];
  const f32x4 zero4 = {0.f, 0.f, 0.f, 0.f};
#pragma unroll
  for (int mi = 0; mi < 4; ++mi)
#pragma unroll
    for (int ni = 0; ni < 4; ++ni) acc[mi][ni] = zero4;

  auto stage = [&](int bufi, int kt) {
    const unsigned short* ga = Abase + kt * 64;
#pragma unroll
    for (int it = 0; it < 8; ++it) {
      __builtin_amdgcn_global_load_lds(
          (AS1Q unsigned int*)(ga + (size_t)it * 8 * K),
          (AS3Q unsigned int*)&Al[bufi][wave * 64 + it * 8][0],
          16, 0, 0);
    }
    const float* gb = Bbase + (size_t)kt * 64 * N;
    float v[16];
#pragma unroll
    for (int jj = 0; jj < 16; ++jj) v[jj] = nvalid ? gb[(size_t)jj * N] : 0.f;
    ushort8 p0, p1;
#pragma unroll
    for (int jj = 0; jj < 8; ++jj) { p0[jj] = f2bf(v[jj]); p1[jj] = f2bf(v[jj + 8]); }
    const int sl0 = ((kq * 2) ^ (bn & 7)) * 8;       // 8-elem (16B) chunk slots
    const int sl1 = ((kq * 2 + 1) ^ (bn & 7)) * 8;
    *(ushort8*)&Bl[bufi][bn][sl0] = p0;
    *(ushort8*)&Bl[bufi][bn][sl1] = p1;
  };

  auto compute = [&](int bufi) {
#pragma unroll
    for (int ki = 0; ki < 2; ++ki) {
      const int ch = ((ki * 4 + hi4) ^ r7) * 8;      // un-swizzle on read
      short8 af[4], bfv[4];
#pragma unroll
      for (int mi = 0; mi < 4; ++mi)
        af[mi] = *(const short8*)&Al[bufi][wave * 64 + mi * 16 + r15][ch];
#pragma unroll
      for (int ni = 0; ni < 4; ++ni)
        bfv[ni] = *(const short8*)&Bl[bufi][ni * 16 + r15][ch];
#pragma unroll
      for (int mi = 0; mi < 4; ++mi)
#pragma unroll
        for (int ni = 0; ni < 4; ++ni)
          acc[mi][ni] = __builtin_amdgcn_mfma_f32_16x16x32_bf16(af[mi], bfv[ni], acc[mi][ni], 0, 0, 0);
    }
  };

  stage(0, kt0);
  __syncthreads();
  int buf = 0;
  for (int kt = kt0; kt < kt1; ++kt) {
    if (kt + 1 < kt1) stage(buf ^ 1, kt + 1);
    compute(buf);
    __syncthreads();
    buf ^= 1;
  }

  // C/D layout: col = lane&15, row = (lane>>4)*4 + rr   [m89-verified]
  float* Pp = P + (size_t)sp * 256 * NPAD + n0;
#pragma unroll
  for (int mi = 0; mi < 4; ++mi) {
    const int row = wave * 64 + mi * 16 + hi4 * 4;
#pragma unroll
    for (int ni = 0; ni < 4; ++ni) {
#pragma unroll
      for (int rr = 0; rr < 4; ++rr)
        Pp[(size_t)(row + rr) * NPAD + ni * 16 + r15] = acc[mi][ni][rr];
    }
  }
}

// ---------------------------------------------------------------------------
// Reduce split-K partials + Omega-blended bias; then either
//  - ELU + write swizzled bf16 mixed input for next layer (xnext != nullptr)
//  - or write final fp32 output (Yout != nullptr)
// ---------------------------------------------------------------------------
__global__ __launch_bounds__(256)
void reduce_mix_kernel(const float* __restrict__ P, const float* __restrict__ Omega,
                       const float* __restrict__ bias, unsigned short* __restrict__ xnext,
                       float* __restrict__ Yout, int N, int NPAD)
{
  const int n = blockIdx.x * 256 + threadIdx.x;
  const int b = blockIdx.y;
  if (n >= N) return;
  float acc = 0.f;
#pragma unroll 4
  for (int s = 0; s < SPLITK; ++s) acc += P[((size_t)s * 256 + b) * NPAD + n];
  float om[8];
#pragma unroll
  for (int e = 0; e < 8; ++e) om[e] = Omega[b * 8 + e];
  float bs = 0.f;
#pragma unroll
  for (int e = 0; e < 8; ++e) bs += om[e] * bias[(size_t)e * N + n];
  float y = acc + bs;
  if (Yout) { Yout[(size_t)b * N + n] = y; return; }
  float a = (y > 0.f) ? y : expm1f(y);            // ELU
  const int swz = (b & 7) << 3;
  unsigned short* row = xnext + (size_t)b * K2_N;
#pragma unroll
  for (int e = 0; e < 8; ++e)
    row[(e * HID_N + n) ^ swz] = f2bf(om[e] * a);
}

// ---------------------------------------------------------------------------
extern "C" void kernel_launch(void* const* d_in, const int* in_sizes, int n_in,
                              void* d_out, int out_size, void* d_ws, size_t ws_size,
                              hipStream_t stream) {
  const float* X    = (const float*)d_in[0];
  const float* Wih0 = (const float*)d_in[1];
  const float* Whh0 = (const float*)d_in[2];
  const float* bih0 = (const float*)d_in[3];
  const float* bhh0 = (const float*)d_in[4];
  const float* Wih1 = (const float*)d_in[5];
  const float* Whh1 = (const float*)d_in[6];
  const float* bih1 = (const float*)d_in[7];
  const float* bhh1 = (const float*)d_in[8];
  const float* w1   = (const float*)d_in[9];
  const float* b1   = (const float*)d_in[10];
  const float* w2   = (const float*)d_in[11];
  const float* b2   = (const float*)d_in[12];
  const float* w3   = (const float*)d_in[13];
  const float* b3   = (const float*)d_in[14];

  char* ws = (char*)d_ws;
  float* Omega        = (float*)ws;                                  // 8 KB
  unsigned short* xt1 = (unsigned short*)(ws + 8192);                // 256*7936*2 = 4,063,232
  unsigned short* xt2 = (unsigned short*)(ws + 8192 + 4063232);      // 256*6016*2 = 3,080,192
  unsigned short* xt3 = (unsigned short*)(ws + 8192 + 4063232 + 3080192);
  float* P            = (float*)(ws + 8192 + 4063232 + 3080192 + 3080192); // 20*256*768*4 = 15,728,640

  gru_omega_kernel<<<32, 64, 0, stream>>>(X, Wih0, Whh0, bih0, bhh0,
                                          Wih1, Whh1, bih1, bhh1, Omega);
  mix1_kernel<<<992, 256, 0, stream>>>(X, Omega, xt1);

  // layer 1: 256 x 7936 @ 7936 x 752
  gemm_splitk<<<dim3(12, SPLITK), 256, 0, stream>>>(xt1, w1, P, K1_N, HID_N, 768);
  reduce_mix_kernel<<<dim3(3, 256), 256, 0, stream>>>(P, Omega, b1, xt2, nullptr, HID_N, 768);

  // layer 2: 256 x 6016 @ 6016 x 752
  gemm_splitk<<<dim3(12, SPLITK), 256, 0, stream>>>(xt2, w2, P, K2_N, HID_N, 768);
  reduce_mix_kernel<<<dim3(3, 256), 256, 0, stream>>>(P, Omega, b2, xt3, nullptr, HID_N, 768);

  // layer 3: 256 x 6016 @ 6016 x 512
  gemm_splitk<<<dim3(8, SPLITK), 256, 0, stream>>>(xt3, w3, P, K2_N, 512, 512);
  reduce_mix_kernel<<<dim3(2, 256), 256, 0, stream>>>(P, Omega, b3, nullptr, (float*)d_out, 512, 512);
}

// Round 5
// 95.121 us; speedup vs baseline: 1.1729x; 1.0299x over previous
//
#include <hip/hip_runtime.h>
#include <cstdint>
#include <cstddef>

typedef __attribute__((ext_vector_type(8))) short short8;
typedef __attribute__((ext_vector_type(8))) unsigned short ushort8;
typedef __attribute__((ext_vector_type(4))) float f32x4;

#define AS1Q const __attribute__((address_space(1)))
#define AS3Q __attribute__((address_space(3)))

constexpr int T_N = 60, IN_N = 520, MOE_RAW_N = 512, MOE_IN_N = 992;
constexpr int HID_N = 752, E_N = 8;
constexpr int K1_N = 7936, K2_N = 6016;   // 8*992, 8*752
constexpr int SPLITK = 20;

static __device__ __forceinline__ unsigned short f2bf(float f) {
  unsigned int u = __float_as_uint(f);
  return (unsigned short)((u + 0x7fffu + ((u >> 16) & 1u)) >> 16);   // RNE
}
static __device__ __forceinline__ float sigf(float x) {
  return __fdividef(1.f, 1.f + __expf(-x));
}
static __device__ __forceinline__ float tanh_fast(float x) {
  return 2.f * __fdividef(1.f, 1.f + __expf(-2.f * x)) - 1.f;
}

// DPP row-rotate by R within the 16-lane row (pure VALU — no LDS pipe).
template<int R>
static __device__ __forceinline__ float rotf(float v) {
  return __int_as_float(__builtin_amdgcn_update_dpp(
      0, __float_as_int(v), 0x120 | R, 0xF, 0xF, true));
}
static __device__ __forceinline__ void rot8(float (&d)[8], float v) {
  d[0] = v;
  d[1] = rotf<1>(v); d[2] = rotf<2>(v); d[3] = rotf<3>(v);
  d[4] = rotf<4>(v); d[5] = rotf<5>(v); d[6] = rotf<6>(v); d[7] = rotf<7>(v);
}

// ---------------------------------------------------------------------------
// GRU (2 layers, H=8) -> Omega = softmax(h2[:, -1, :]).
// ROUND-5: shuffle-free serial chain. 16 lanes per sample (h replicated in
// both 8-lane halves of a DPP row), 4 samples/wave, 64 blocks. All cross-lane
// traffic is v_mov_dpp row_ror (VALU, 2cy) instead of ds_bpermute (~120cy
// single-wave LDS latency). Rounds 1-4 were pinned at ~1500cy/step == 16
// bpermutes x ~100cy; this removes the LDS pipe from the chain entirely.
// Weight gather index matches the DPP direction via a runtime 2-instr probe.
// ---------------------------------------------------------------------------
__global__ __launch_bounds__(64, 1)
void gru_omega_kernel(const float* __restrict__ X,
                      const float* __restrict__ Wih0, const float* __restrict__ Whh0,
                      const float* __restrict__ bih0, const float* __restrict__ bhh0,
                      const float* __restrict__ Wih1, const float* __restrict__ Whh1,
                      const float* __restrict__ bih1, const float* __restrict__ bhh1,
                      float* __restrict__ Omega)
{
  __shared__ float xl[T_N][64];   // 15 KB; xl[t][lane] = x_t[lane&7] (replicated)

  const int lane = threadIdx.x;
  const int j = lane & 7;          // hidden unit
  const int s = lane >> 4;         // sample within block (4/wave)
  const int b = blockIdx.x * 4 + s;

  // ---- stage gate-input slice: 60 x global_load_lds (width 4, lane-linear) ----
  const float* xsrc = X + (size_t)b * (T_N * IN_N) + MOE_RAW_N + j;
#pragma unroll
  for (int t = 0; t < T_N; ++t) {
    __builtin_amdgcn_global_load_lds((AS1Q unsigned int*)(xsrc + t * IN_N),
                                     (AS3Q unsigned int*)&xl[t][0], 4, 0, 0);
  }

  // ---- probe DPP row_ror direction (ror:1 -> j-1 or j+1; select gather idx) ----
  const int got = __builtin_amdgcn_update_dpp(0, j, 0x121, 0xF, 0xF, true);
  const bool plus = (got == ((j + 1) & 7));

  // ---- gather rotation-ordered weights: w*[r] pairs with rot_r(h) = h[(j∓r)&7] ----
  float wi0r[8], wi0z[8], wi0n[8], wh0r[8], wh0z[8], wh0n[8];
  float wi1r[8], wi1z[8], wi1n[8], wh1r[8], wh1z[8], wh1n[8];
#pragma unroll
  for (int r = 0; r < 8; ++r) {
    const int i = plus ? ((j + r) & 7) : ((j - r) & 7);
    wi0r[r] = Wih0[j * 8 + i]; wi0z[r] = Wih0[(8 + j) * 8 + i]; wi0n[r] = Wih0[(16 + j) * 8 + i];
    wh0r[r] = Whh0[j * 8 + i]; wh0z[r] = Whh0[(8 + j) * 8 + i]; wh0n[r] = Whh0[(16 + j) * 8 + i];
    wi1r[r] = Wih1[j * 8 + i]; wi1z[r] = Wih1[(8 + j) * 8 + i]; wi1n[r] = Wih1[(16 + j) * 8 + i];
    wh1r[r] = Whh1[j * 8 + i]; wh1z[r] = Whh1[(8 + j) * 8 + i]; wh1n[r] = Whh1[(16 + j) * 8 + i];
  }
  const float br0 = bih0[j] + bhh0[j], bz0 = bih0[8 + j] + bhh0[8 + j];
  const float bin0 = bih0[16 + j],     bhn0 = bhh0[16 + j];
  const float br1 = bih1[j] + bhh1[j], bz1 = bih1[8 + j] + bhh1[8 + j];
  const float bin1 = bih1[16 + j],     bhn1 = bhh1[16 + j];

  __syncthreads();   // drain the global_load_lds batch

  float h1 = 0.f, h2 = 0.f;
  float xcur = xl[0][lane];

#pragma unroll 1                    // body must stay < L1I
  for (int t = 0; t < T_N; ++t) {
    const float xnext = xl[(t + 1 < T_N) ? t + 1 : t][lane];  // prefetch

    // ---- layer 0: x(t) and h1(t-1), both via DPP rotations ----
    float rx[8]; rot8(rx, xcur);
    float rh[8]; rot8(rh, h1);
    float grA = br0, gzA = bz0, gnA = bin0, hnA = bhn0;
    float grB = 0.f, gzB = 0.f, gnB = 0.f, hnB = 0.f;
#pragma unroll
    for (int r = 0; r < 4; ++r) {
      grA += wi0r[r] * rx[r];     gzA += wi0z[r] * rx[r];     gnA += wi0n[r] * rx[r];
      grA += wh0r[r] * rh[r];     gzA += wh0z[r] * rh[r];     hnA += wh0n[r] * rh[r];
      grB += wi0r[4+r] * rx[4+r]; gzB += wi0z[4+r] * rx[4+r]; gnB += wi0n[4+r] * rx[4+r];
      grB += wh0r[4+r] * rh[4+r]; gzB += wh0z[4+r] * rh[4+r]; hnB += wh0n[4+r] * rh[4+r];
    }
    {
      const float gr = grA + grB, gz = gzA + gzB, gn = gnA + gnB, hn = hnA + hnB;
      const float r0 = sigf(gr), z0 = sigf(gz);
      const float n0 = tanh_fast(gn + r0 * hn);
      h1 = (1.f - z0) * n0 + z0 * h1;
    }

    // ---- layer 1: h1(t) and h2(t-1) ----
    float ri[8]; rot8(ri, h1);
    float rh2[8]; rot8(rh2, h2);
    float grA1 = br1, gzA1 = bz1, gnA1 = bin1, hnA1 = bhn1;
    float grB1 = 0.f, gzB1 = 0.f, gnB1 = 0.f, hnB1 = 0.f;
#pragma unroll
    for (int r = 0; r < 4; ++r) {
      grA1 += wi1r[r] * ri[r];     gzA1 += wi1z[r] * ri[r];     gnA1 += wi1n[r] * ri[r];
      grA1 += wh1r[r] * rh2[r];    gzA1 += wh1z[r] * rh2[r];    hnA1 += wh1n[r] * rh2[r];
      grB1 += wi1r[4+r] * ri[4+r]; gzB1 += wi1z[4+r] * ri[4+r]; gnB1 += wi1n[4+r] * ri[4+r];
      grB1 += wh1r[4+r] * rh2[4+r];gzB1 += wh1z[4+r] * rh2[4+r];hnB1 += wh1n[4+r] * rh2[4+r];
    }
    {
      const float gr = grA1 + grB1, gz = gzA1 + gzB1, gn = gnA1 + gnB1, hn = hnA1 + hnB1;
      const float r1 = sigf(gr), z1 = sigf(gz);
      const float n1 = tanh_fast(gn + r1 * hn);
      h2 = (1.f - z1) * n1 + z1 * h2;
    }

    xcur = xnext;
  }

  // ---- softmax over the 8 hidden units, fully in-register via rotations ----
  float rv[8]; rot8(rv, h2);
  float m = rv[0];
#pragma unroll
  for (int r = 1; r < 8; ++r) m = fmaxf(m, rv[r]);
  const float ej = __expf(h2 - m);
  float re[8]; rot8(re, ej);
  float sden = 0.f;
#pragma unroll
  for (int r = 0; r < 8; ++r) sden += re[r];
  if (!(lane & 8)) Omega[b * 8 + j] = __fdividef(ej, sden);
}

// ---------------------------------------------------------------------------
// Build x~1[b, (e*992+i) ^ swz] = bf16(Omega[b,e] * Xm[b,i])  (swizzled bf16)
// Xm[b,i] = X[b,59,i] (i<512) else X[b,(i-512)/8, 512+(i-512)%8]
// ---------------------------------------------------------------------------
__global__ __launch_bounds__(256)
void mix1_kernel(const float* __restrict__ X, const float* __restrict__ Omega,
                 unsigned short* __restrict__ xt1)
{
  const int idx = blockIdx.x * 256 + threadIdx.x;      // 256*992 total
  const int b = idx / MOE_IN_N;
  const int i = idx - b * MOE_IN_N;
  const float* Xb = X + (size_t)b * (T_N * IN_N);
  float xm;
  if (i < MOE_RAW_N) {
    xm = Xb[(T_N - 1) * IN_N + i];
  } else {
    const int t = (i - MOE_RAW_N) >> 3, g = (i - MOE_RAW_N) & 7;
    xm = Xb[t * IN_N + MOE_RAW_N + g];
  }
  const int swz = (b & 7) << 3;
  unsigned short* row = xt1 + (size_t)b * K1_N;
#pragma unroll
  for (int e = 0; e < 8; ++e) {
    float w = Omega[b * 8 + e];
    row[(e * MOE_IN_N + i) ^ swz] = f2bf(w * xm);
  }
}

// ---------------------------------------------------------------------------
// Split-K GEMM: P[sp][256][NPAD] += A(bf16, swizzled [256][K]) * Bw(fp32 [K][N])
// BM=256 (full M), BN=64, BK=64, 4 waves, wave = 64 rows x 64 cols.
// A staged via global_load_lds (16B), B reg-staged fp32->bf16, transposed,
// XOR-swizzled LDS ( chunk ^= row&7 within 128B rows ).
// ---------------------------------------------------------------------------
__global__ __launch_bounds__(256)
void gemm_splitk(const unsigned short* __restrict__ A,
                 const float* __restrict__ Bw,
                 float* __restrict__ P,
                 int K, int N, int NPAD)
{
  __shared__ unsigned short Al[2][256][64];   // 64 KB
  __shared__ unsigned short Bl[2][64][64];    // 16 KB  (Bl[n][k], transposed)

  const int tid = threadIdx.x;
  const int lane = tid & 63;
  const int wave = tid >> 6;
  const int nt = blockIdx.x, sp = blockIdx.y;
  const int n0 = nt * 64;
  const int KT = K >> 6;
  const int kt0 = (KT * sp) / SPLITK;
  const int kt1 = (KT * (sp + 1)) / SPLITK;

  const int r15 = lane & 15, hi4 = lane >> 4, r7 = lane & 7;

  // A staging: each wave stages its own 64 rows, 8 gload_lds per K-tile
  const unsigned short* Abase = A + (size_t)(wave * 64 + (lane >> 3)) * K + (lane & 7) * 8;
  // B staging: thread t -> col n=t&63, k-quarter kq=t>>6 (16 consecutive k)
  const int bn = lane;
  const int kq = wave;
  const bool nvalid = (n0 + bn) < N;
  const float* Bbase = Bw + (size_t)(kq * 16) * N + (n0 + bn);

  f32x4 acc[4][4];
  const f32x4 zero4 = {0.f, 0.f, 0.f, 0.f};
#pragma unroll
  for (int mi = 0; mi < 4; ++mi)
#pragma unroll
    for (int ni = 0; ni < 4; ++ni) acc[mi][ni] = zero4;

  auto stage = [&](int bufi, int kt) {
    const unsigned short* ga = Abase + kt * 64;
#pragma unroll
    for (int it = 0; it < 8; ++it) {
      __builtin_amdgcn_global_load_lds(
          (AS1Q unsigned int*)(ga + (size_t)it * 8 * K),
          (AS3Q unsigned int*)&Al[bufi][wave * 64 + it * 8][0],
          16, 0, 0);
    }
    const float* gb = Bbase + (size_t)kt * 64 * N;
    float v[16];
#pragma unroll
    for (int jj = 0; jj < 16; ++jj) v[jj] = nvalid ? gb[(size_t)jj * N] : 0.f;
    ushort8 p0, p1;
#pragma unroll
    for (int jj = 0; jj < 8; ++jj) { p0[jj] = f2bf(v[jj]); p1[jj] = f2bf(v[jj + 8]); }
    const int sl0 = ((kq * 2) ^ (bn & 7)) * 8;       // 8-elem (16B) chunk slots
    const int sl1 = ((kq * 2 + 1) ^ (bn & 7)) * 8;
    *(ushort8*)&Bl[bufi][bn][sl0] = p0;
    *(ushort8*)&Bl[bufi][bn][sl1] = p1;
  };

  auto compute = [&](int bufi) {
#pragma unroll
    for (int ki = 0; ki < 2; ++ki) {
      const int ch = ((ki * 4 + hi4) ^ r7) * 8;      // un-swizzle on read
      short8 af[4], bfv[4];
#pragma unroll
      for (int mi = 0; mi < 4; ++mi)
        af[mi] = *(const short8*)&Al[bufi][wave * 64 + mi * 16 + r15][ch];
#pragma unroll
      for (int ni = 0; ni < 4; ++ni)
        bfv[ni] = *(const short8*)&Bl[bufi][ni * 16 + r15][ch];
#pragma unroll
      for (int mi = 0; mi < 4; ++mi)
#pragma unroll
        for (int ni = 0; ni < 4; ++ni)
          acc[mi][ni] = __builtin_amdgcn_mfma_f32_16x16x32_bf16(af[mi], bfv[ni], acc[mi][ni], 0, 0, 0);
    }
  };

  stage(0, kt0);
  __syncthreads();
  int buf = 0;
  for (int kt = kt0; kt < kt1; ++kt) {
    if (kt + 1 < kt1) stage(buf ^ 1, kt + 1);
    compute(buf);
    __syncthreads();
    buf ^= 1;
  }

  // C/D layout: col = lane&15, row = (lane>>4)*4 + rr   [m89-verified]
  float* Pp = P + (size_t)sp * 256 * NPAD + n0;
#pragma unroll
  for (int mi = 0; mi < 4; ++mi) {
    const int row = wave * 64 + mi * 16 + hi4 * 4;
#pragma unroll
    for (int ni = 0; ni < 4; ++ni) {
#pragma unroll
      for (int rr = 0; rr < 4; ++rr)
        Pp[(size_t)(row + rr) * NPAD + ni * 16 + r15] = acc[mi][ni][rr];
    }
  }
}

// ---------------------------------------------------------------------------
// Reduce split-K partials + Omega-blended bias; then either
//  - ELU + write swizzled bf16 mixed input for next layer (xnext != nullptr)
//  - or write final fp32 output (Yout != nullptr)
// ---------------------------------------------------------------------------
__global__ __launch_bounds__(256)
void reduce_mix_kernel(const float* __restrict__ P, const float* __restrict__ Omega,
                       const float* __restrict__ bias, unsigned short* __restrict__ xnext,
                       float* __restrict__ Yout, int N, int NPAD)
{
  const int n = blockIdx.x * 256 + threadIdx.x;
  const int b = blockIdx.y;
  if (n >= N) return;
  float acc = 0.f;
#pragma unroll 4
  for (int s = 0; s < SPLITK; ++s) acc += P[((size_t)s * 256 + b) * NPAD + n];
  float om[8];
#pragma unroll
  for (int e = 0; e < 8; ++e) om[e] = Omega[b * 8 + e];
  float bs = 0.f;
#pragma unroll
  for (int e = 0; e < 8; ++e) bs += om[e] * bias[(size_t)e * N + n];
  float y = acc + bs;
  if (Yout) { Yout[(size_t)b * N + n] = y; return; }
  float a = (y > 0.f) ? y : expm1f(y);            // ELU
  const int swz = (b & 7) << 3;
  unsigned short* row = xnext + (size_t)b * K2_N;
#pragma unroll
  for (int e = 0; e < 8; ++e)
    row[(e * HID_N + n) ^ swz] = f2bf(om[e] * a);
}

// ---------------------------------------------------------------------------
extern "C" void kernel_launch(void* const* d_in, const int* in_sizes, int n_in,
                              void* d_out, int out_size, void* d_ws, size_t ws_size,
                              hipStream_t stream) {
  const float* X    = (const float*)d_in[0];
  const float* Wih0 = (const float*)d_in[1];
  const float* Whh0 = (const float*)d_in[2];
  const float* bih0 = (const float*)d_in[3];
  const float* bhh0 = (const float*)d_in[4];
  const float* Wih1 = (const float*)d_in[5];
  const float* Whh1 = (const float*)d_in[6];
  const float* bih1 = (const float*)d_in[7];
  const float* bhh1 = (const float*)d_in[8];
  const float* w1   = (const float*)d_in[9];
  const float* b1   = (const float*)d_in[10];
  const float* w2   = (const float*)d_in[11];
  const float* b2   = (const float*)d_in[12];
  const float* w3   = (const float*)d_in[13];
  const float* b3   = (const float*)d_in[14];

  char* ws = (char*)d_ws;
  float* Omega        = (float*)ws;                                  // 8 KB
  unsigned short* xt1 = (unsigned short*)(ws + 8192);                // 256*7936*2 = 4,063,232
  unsigned short* xt2 = (unsigned short*)(ws + 8192 + 4063232);      // 256*6016*2 = 3,080,192
  unsigned short* xt3 = (unsigned short*)(ws + 8192 + 4063232 + 3080192);
  float* P            = (float*)(ws + 8192 + 4063232 + 3080192 + 3080192); // 20*256*768*4 = 15,728,640

  gru_omega_kernel<<<64, 64, 0, stream>>>(X, Wih0, Whh0, bih0, bhh0,
                                          Wih1, Whh1, bih1, bhh1, Omega);
  mix1_kernel<<<992, 256, 0, stream>>>(X, Omega, xt1);

  // layer 1: 256 x 7936 @ 7936 x 752
  gemm_splitk<<<dim3(12, SPLITK), 256, 0, stream>>>(xt1, w1, P, K1_N, HID_N, 768);
  reduce_mix_kernel<<<dim3(3, 256), 256, 0, stream>>>(P, Omega, b1, xt2, nullptr, HID_N, 768);

  // layer 2: 256 x 6016 @ 6016 x 752
  gemm_splitk<<<dim3(12, SPLITK), 256, 0, stream>>>(xt2, w2, P, K2_N, HID_N, 768);
  reduce_mix_kernel<<<dim3(3, 256), 256, 0, stream>>>(P, Omega, b2, xt3, nullptr, HID_N, 768);

  // layer 3: 256 x 6016 @ 6016 x 512
  gemm_splitk<<<dim3(8, SPLITK), 256, 0, stream>>>(xt3, w3, P, K2_N, 512, 512);
  reduce_mix_kernel<<<dim3(2, 256), 256, 0, stream>>>(P, Omega, b3, nullptr, (float*)d_out, 512, 512);
}

// Round 6
// 94.159 us; speedup vs baseline: 1.1849x; 1.0102x over previous
//
#include <hip/hip_runtime.h>
#include <cstdint>
#include <cstddef>

typedef __attribute__((ext_vector_type(8))) short short8;
typedef __attribute__((ext_vector_type(8))) unsigned short ushort8;
typedef __attribute__((ext_vector_type(4))) float f32x4;

#define AS1Q const __attribute__((address_space(1)))
#define AS3Q __attribute__((address_space(3)))

constexpr int T_N = 60, IN_N = 520, MOE_RAW_N = 512, MOE_IN_N = 992;
constexpr int HID_N = 752, E_N = 8;
constexpr int K1_N = 7936, K2_N = 6016;   // 8*992, 8*752
constexpr int SPLITK = 20;

static __device__ __forceinline__ unsigned short f2bf(float f) {
  unsigned int u = __float_as_uint(f);
  return (unsigned short)((u + 0x7fffu + ((u >> 16) & 1u)) >> 16);   // RNE
}
static __device__ __forceinline__ float sigf(float x) {
  return __fdividef(1.f, 1.f + __expf(-x));
}
static __device__ __forceinline__ float tanh_fast(float x) {
  return 2.f * __fdividef(1.f, 1.f + __expf(-2.f * x)) - 1.f;
}

// DPP row-rotate by R within the 16-lane row (pure VALU — no LDS pipe).
template<int R>
static __device__ __forceinline__ float rotf(float v) {
  return __int_as_float(__builtin_amdgcn_update_dpp(
      0, __float_as_int(v), 0x120 | R, 0xF, 0xF, true));
}
static __device__ __forceinline__ void rot8(float (&d)[8], float v) {
  d[0] = v;
  d[1] = rotf<1>(v); d[2] = rotf<2>(v); d[3] = rotf<3>(v);
  d[4] = rotf<4>(v); d[5] = rotf<5>(v); d[6] = rotf<6>(v); d[7] = rotf<7>(v);
}

// ---------------------------------------------------------------------------
// GRU (2 layers, H=8) -> Omega = softmax(h2[:, -1, :]).
// ROUND-6: SOFTWARE-PIPELINED LAYERS. Rounds 1-5 were pinned at ~1200cy/step
// because layer0 and layer1 ran back-to-back: two serial transcendental
// chains per step. This iteration computes layer0(step t) and layer1(step
// t-1) as two INDEPENDENT dataflow chains in one loop body (layer1 needs
// only h1(t-1), h2(t-2)) -> critical path ~= max(chain0, chain1), trans
// stalls of one chain filled by the other's FMAs. rot8(h1) is shared
// (layer0 recurrence rotations == layer1 input rotations): 21 DPP/step.
// 61 iterations; h2 forced to 0 after the t=0 warm-up; h2(59) produced at
// t=60. 16 lanes/sample (period-8 replication), 4 samples/wave, 64 blocks.
// ---------------------------------------------------------------------------
__global__ __launch_bounds__(64, 1)
void gru_omega_kernel(const float* __restrict__ X,
                      const float* __restrict__ Wih0, const float* __restrict__ Whh0,
                      const float* __restrict__ bih0, const float* __restrict__ bhh0,
                      const float* __restrict__ Wih1, const float* __restrict__ Whh1,
                      const float* __restrict__ bih1, const float* __restrict__ bhh1,
                      float* __restrict__ Omega)
{
  __shared__ float xl[T_N][64];   // 15 KB; xl[t][lane] = x_t[lane&7] (replicated)

  const int lane = threadIdx.x;
  const int j = lane & 7;          // hidden unit
  const int s = lane >> 4;         // sample within block (4/wave)
  const int b = blockIdx.x * 4 + s;

  // ---- stage gate-input slice: 60 x global_load_lds (width 4, lane-linear) ----
  const float* xsrc = X + (size_t)b * (T_N * IN_N) + MOE_RAW_N + j;
#pragma unroll
  for (int t = 0; t < T_N; ++t) {
    __builtin_amdgcn_global_load_lds((AS1Q unsigned int*)(xsrc + t * IN_N),
                                     (AS3Q unsigned int*)&xl[t][0], 4, 0, 0);
  }

  // ---- probe DPP row_ror direction (ror:1 -> j-1 or j+1; select gather idx) ----
  const int got = __builtin_amdgcn_update_dpp(0, j, 0x121, 0xF, 0xF, true);
  const bool plus = (got == ((j + 1) & 7));

  // ---- gather rotation-ordered weights: w*[r] pairs with rot_r(h) ----
  float wi0r[8], wi0z[8], wi0n[8], wh0r[8], wh0z[8], wh0n[8];
  float wi1r[8], wi1z[8], wi1n[8], wh1r[8], wh1z[8], wh1n[8];
#pragma unroll
  for (int r = 0; r < 8; ++r) {
    const int i = plus ? ((j + r) & 7) : ((j - r) & 7);
    wi0r[r] = Wih0[j * 8 + i]; wi0z[r] = Wih0[(8 + j) * 8 + i]; wi0n[r] = Wih0[(16 + j) * 8 + i];
    wh0r[r] = Whh0[j * 8 + i]; wh0z[r] = Whh0[(8 + j) * 8 + i]; wh0n[r] = Whh0[(16 + j) * 8 + i];
    wi1r[r] = Wih1[j * 8 + i]; wi1z[r] = Wih1[(8 + j) * 8 + i]; wi1n[r] = Wih1[(16 + j) * 8 + i];
    wh1r[r] = Whh1[j * 8 + i]; wh1z[r] = Whh1[(8 + j) * 8 + i]; wh1n[r] = Whh1[(16 + j) * 8 + i];
  }
  const float br0 = bih0[j] + bhh0[j], bz0 = bih0[8 + j] + bhh0[8 + j];
  const float bin0 = bih0[16 + j],     bhn0 = bhh0[16 + j];
  const float br1 = bih1[j] + bhh1[j], bz1 = bih1[8 + j] + bhh1[8 + j];
  const float bin1 = bih1[16 + j],     bhn1 = bhh1[16 + j];

  __syncthreads();   // drain the global_load_lds batch

  float h1 = 0.f, h2 = 0.f;
  float xcur = xl[0][lane];

#pragma unroll 1                    // body must stay < L1I
  for (int t = 0; t <= T_N; ++t) {  // 61 iterations (pipeline drain)
    const float xnext = xl[(t + 1 < T_N) ? t + 1 : T_N - 1][lane];  // prefetch

    // shared rotations: rx feeds chainA; rh1 feeds BOTH chains; rh2 chainB
    float rx[8];  rot8(rx, xcur);
    float rh1[8]; rot8(rh1, h1);
    float rh2[8]; rot8(rh2, h2);

    // ---- chain A: layer 0, step t  (input x(t), state h1(t-1)) ----
    float grA = br0, gzA = bz0, gnA = bin0, hnA = bhn0;
    float grB = 0.f, gzB = 0.f, gnB = 0.f, hnB = 0.f;
#pragma unroll
    for (int r = 0; r < 4; ++r) {
      grA += wi0r[r] * rx[r];     gzA += wi0z[r] * rx[r];     gnA += wi0n[r] * rx[r];
      grA += wh0r[r] * rh1[r];    gzA += wh0z[r] * rh1[r];    hnA += wh0n[r] * rh1[r];
      grB += wi0r[4+r] * rx[4+r]; gzB += wi0z[4+r] * rx[4+r]; gnB += wi0n[4+r] * rx[4+r];
      grB += wh0r[4+r] * rh1[4+r];gzB += wh0z[4+r] * rh1[4+r];hnB += wh0n[4+r] * rh1[4+r];
    }
    float h1n;
    {
      const float gr = grA + grB, gz = gzA + gzB, gn = gnA + gnB, hn = hnA + hnB;
      const float r0 = sigf(gr), z0 = sigf(gz);
      const float n0 = tanh_fast(gn + r0 * hn);
      h1n = (1.f - z0) * n0 + z0 * h1;
    }

    // ---- chain B: layer 1, step t-1  (input h1(t-1), state h2(t-2)) ----
    float grA1 = br1, gzA1 = bz1, gnA1 = bin1, hnA1 = bhn1;
    float grB1 = 0.f, gzB1 = 0.f, gnB1 = 0.f, hnB1 = 0.f;
#pragma unroll
    for (int r = 0; r < 4; ++r) {
      grA1 += wi1r[r] * rh1[r];     gzA1 += wi1z[r] * rh1[r];     gnA1 += wi1n[r] * rh1[r];
      grA1 += wh1r[r] * rh2[r];     gzA1 += wh1z[r] * rh2[r];     hnA1 += wh1n[r] * rh2[r];
      grB1 += wi1r[4+r] * rh1[4+r]; gzB1 += wi1z[4+r] * rh1[4+r]; gnB1 += wi1n[4+r] * rh1[4+r];
      grB1 += wh1r[4+r] * rh2[4+r]; gzB1 += wh1z[4+r] * rh2[4+r]; hnB1 += wh1n[4+r] * rh2[4+r];
    }
    float h2n;
    {
      const float gr = grA1 + grB1, gz = gzA1 + gzB1, gn = gnA1 + gnB1, hn = hnA1 + hnB1;
      const float r1 = sigf(gr), z1 = sigf(gz);
      const float n1 = tanh_fast(gn + r1 * hn);
      h2n = (1.f - z1) * n1 + z1 * h2;
    }

    h1 = h1n;
    h2 = (t == 0) ? 0.f : h2n;   // t=0 warm-up processed step -1: discard
    xcur = xnext;
  }

  // ---- softmax over the 8 hidden units, fully in-register via rotations ----
  float rv[8]; rot8(rv, h2);
  float m = rv[0];
#pragma unroll
  for (int r = 1; r < 8; ++r) m = fmaxf(m, rv[r]);
  const float ej = __expf(h2 - m);
  float re[8]; rot8(re, ej);
  float sden = 0.f;
#pragma unroll
  for (int r = 0; r < 8; ++r) sden += re[r];
  if (!(lane & 8)) Omega[b * 8 + j] = __fdividef(ej, sden);
}

// ---------------------------------------------------------------------------
// Build x~1[b, (e*992+i) ^ swz] = bf16(Omega[b,e] * Xm[b,i])  (swizzled bf16)
// Xm[b,i] = X[b,59,i] (i<512) else X[b,(i-512)/8, 512+(i-512)%8]
// ---------------------------------------------------------------------------
__global__ __launch_bounds__(256)
void mix1_kernel(const float* __restrict__ X, const float* __restrict__ Omega,
                 unsigned short* __restrict__ xt1)
{
  const int idx = blockIdx.x * 256 + threadIdx.x;      // 256*992 total
  const int b = idx / MOE_IN_N;
  const int i = idx - b * MOE_IN_N;
  const float* Xb = X + (size_t)b * (T_N * IN_N);
  float xm;
  if (i < MOE_RAW_N) {
    xm = Xb[(T_N - 1) * IN_N + i];
  } else {
    const int t = (i - MOE_RAW_N) >> 3, g = (i - MOE_RAW_N) & 7;
    xm = Xb[t * IN_N + MOE_RAW_N + g];
  }
  const int swz = (b & 7) << 3;
  unsigned short* row = xt1 + (size_t)b * K1_N;
#pragma unroll
  for (int e = 0; e < 8; ++e) {
    float w = Omega[b * 8 + e];
    row[(e * MOE_IN_N + i) ^ swz] = f2bf(w * xm);
  }
}

// ---------------------------------------------------------------------------
// Split-K GEMM: P[sp][256][NPAD] += A(bf16, swizzled [256][K]) * Bw(fp32 [K][N])
// BM=256 (full M), BN=64, BK=64, 4 waves, wave = 64 rows x 64 cols.
// A staged via global_load_lds (16B), B reg-staged fp32->bf16, transposed,
// XOR-swizzled LDS ( chunk ^= row&7 within 128B rows ).
// ---------------------------------------------------------------------------
__global__ __launch_bounds__(256)
void gemm_splitk(const unsigned short* __restrict__ A,
                 const float* __restrict__ Bw,
                 float* __restrict__ P,
                 int K, int N, int NPAD)
{
  __shared__ unsigned short Al[2][256][64];   // 64 KB
  __shared__ unsigned short Bl[2][64][64];    // 16 KB  (Bl[n][k], transposed)

  const int tid = threadIdx.x;
  const int lane = tid & 63;
  const int wave = tid >> 6;
  const int nt = blockIdx.x, sp = blockIdx.y;
  const int n0 = nt * 64;
  const int KT = K >> 6;
  const int kt0 = (KT * sp) / SPLITK;
  const int kt1 = (KT * (sp + 1)) / SPLITK;

  const int r15 = lane & 15, hi4 = lane >> 4, r7 = lane & 7;

  // A staging: each wave stages its own 64 rows, 8 gload_lds per K-tile
  const unsigned short* Abase = A + (size_t)(wave * 64 + (lane >> 3)) * K + (lane & 7) * 8;
  // B staging: thread t -> col n=t&63, k-quarter kq=t>>6 (16 consecutive k)
  const int bn = lane;
  const int kq = wave;
  const bool nvalid = (n0 + bn) < N;
  const float* Bbase = Bw + (size_t)(kq * 16) * N + (n0 + bn);

  f32x4 acc[4][4];
  const f32x4 zero4 = {0.f, 0.f, 0.f, 0.f};
#pragma unroll
  for (int mi = 0; mi < 4; ++mi)
#pragma unroll
    for (int ni = 0; ni < 4; ++ni) acc[mi][ni] = zero4;

  auto stage = [&](int bufi, int kt) {
    const unsigned short* ga = Abase + kt * 64;
#pragma unroll
    for (int it = 0; it < 8; ++it) {
      __builtin_amdgcn_global_load_lds(
          (AS1Q unsigned int*)(ga + (size_t)it * 8 * K),
          (AS3Q unsigned int*)&Al[bufi][wave * 64 + it * 8][0],
          16, 0, 0);
    }
    const float* gb = Bbase + (size_t)kt * 64 * N;
    float v[16];
#pragma unroll
    for (int jj = 0; jj < 16; ++jj) v[jj] = nvalid ? gb[(size_t)jj * N] : 0.f;
    ushort8 p0, p1;
#pragma unroll
    for (int jj = 0; jj < 8; ++jj) { p0[jj] = f2bf(v[jj]); p1[jj] = f2bf(v[jj + 8]); }
    const int sl0 = ((kq * 2) ^ (bn & 7)) * 8;       // 8-elem (16B) chunk slots
    const int sl1 = ((kq * 2 + 1) ^ (bn & 7)) * 8;
    *(ushort8*)&Bl[bufi][bn][sl0] = p0;
    *(ushort8*)&Bl[bufi][bn][sl1] = p1;
  };

  auto compute = [&](int bufi) {
#pragma unroll
    for (int ki = 0; ki < 2; ++ki) {
      const int ch = ((ki * 4 + hi4) ^ r7) * 8;      // un-swizzle on read
      short8 af[4], bfv[4];
#pragma unroll
      for (int mi = 0; mi < 4; ++mi)
        af[mi] = *(const short8*)&Al[bufi][wave * 64 + mi * 16 + r15][ch];
#pragma unroll
      for (int ni = 0; ni < 4; ++ni)
        bfv[ni] = *(const short8*)&Bl[bufi][ni * 16 + r15][ch];
#pragma unroll
      for (int mi = 0; mi < 4; ++mi)
#pragma unroll
        for (int ni = 0; ni < 4; ++ni)
          acc[mi][ni] = __builtin_amdgcn_mfma_f32_16x16x32_bf16(af[mi], bfv[ni], acc[mi][ni], 0, 0, 0);
    }
  };

  stage(0, kt0);
  __syncthreads();
  int buf = 0;
  for (int kt = kt0; kt < kt1; ++kt) {
    if (kt + 1 < kt1) stage(buf ^ 1, kt + 1);
    compute(buf);
    __syncthreads();
    buf ^= 1;
  }

  // C/D layout: col = lane&15, row = (lane>>4)*4 + rr   [m89-verified]
  float* Pp = P + (size_t)sp * 256 * NPAD + n0;
#pragma unroll
  for (int mi = 0; mi < 4; ++mi) {
    const int row = wave * 64 + mi * 16 + hi4 * 4;
#pragma unroll
    for (int ni = 0; ni < 4; ++ni) {
#pragma unroll
      for (int rr = 0; rr < 4; ++rr)
        Pp[(size_t)(row + rr) * NPAD + ni * 16 + r15] = acc[mi][ni][rr];
    }
  }
}

// ---------------------------------------------------------------------------
// Reduce split-K partials + Omega-blended bias; then either
//  - ELU + write swizzled bf16 mixed input for next layer (xnext != nullptr)
//  - or write final fp32 output (Yout != nullptr)
// ---------------------------------------------------------------------------
__global__ __launch_bounds__(256)
void reduce_mix_kernel(const float* __restrict__ P, const float* __restrict__ Omega,
                       const float* __restrict__ bias, unsigned short* __restrict__ xnext,
                       float* __restrict__ Yout, int N, int NPAD)
{
  const int n = blockIdx.x * 256 + threadIdx.x;
  const int b = blockIdx.y;
  if (n >= N) return;
  float acc = 0.f;
#pragma unroll 4
  for (int s = 0; s < SPLITK; ++s) acc += P[((size_t)s * 256 + b) * NPAD + n];
  float om[8];
#pragma unroll
  for (int e = 0; e < 8; ++e) om[e] = Omega[b * 8 + e];
  float bs = 0.f;
#pragma unroll
  for (int e = 0; e < 8; ++e) bs += om[e] * bias[(size_t)e * N + n];
  float y = acc + bs;
  if (Yout) { Yout[(size_t)b * N + n] = y; return; }
  float a = (y > 0.f) ? y : expm1f(y);            // ELU
  const int swz = (b & 7) << 3;
  unsigned short* row = xnext + (size_t)b * K2_N;
#pragma unroll
  for (int e = 0; e < 8; ++e)
    row[(e * HID_N + n) ^ swz] = f2bf(om[e] * a);
}

// ---------------------------------------------------------------------------
extern "C" void kernel_launch(void* const* d_in, const int* in_sizes, int n_in,
                              void* d_out, int out_size, void* d_ws, size_t ws_size,
                              hipStream_t stream) {
  const float* X    = (const float*)d_in[0];
  const float* Wih0 = (const float*)d_in[1];
  const float* Whh0 = (const float*)d_in[2];
  const float* bih0 = (const float*)d_in[3];
  const float* bhh0 = (const float*)d_in[4];
  const float* Wih1 = (const float*)d_in[5];
  const float* Whh1 = (const float*)d_in[6];
  const float* bih1 = (const float*)d_in[7];
  const float* bhh1 = (const float*)d_in[8];
  const float* w1   = (const float*)d_in[9];
  const float* b1   = (const float*)d_in[10];
  const float* w2   = (const float*)d_in[11];
  const float* b2   = (const float*)d_in[12];
  const float* w3   = (const float*)d_in[13];
  const float* b3   = (const float*)d_in[14];

  char* ws = (char*)d_ws;
  float* Omega        = (float*)ws;                                  // 8 KB
  unsigned short* xt1 = (unsigned short*)(ws + 8192);                // 256*7936*2 = 4,063,232
  unsigned short* xt2 = (unsigned short*)(ws + 8192 + 4063232);      // 256*6016*2 = 3,080,192
  unsigned short* xt3 = (unsigned short*)(ws + 8192 + 4063232 + 3080192);
  float* P            = (float*)(ws + 8192 + 4063232 + 3080192 + 3080192); // 20*256*768*4 = 15,728,640

  gru_omega_kernel<<<64, 64, 0, stream>>>(X, Wih0, Whh0, bih0, bhh0,
                                          Wih1, Whh1, bih1, bhh1, Omega);
  mix1_kernel<<<992, 256, 0, stream>>>(X, Omega, xt1);

  // layer 1: 256 x 7936 @ 7936 x 752
  gemm_splitk<<<dim3(12, SPLITK), 256, 0, stream>>>(xt1, w1, P, K1_N, HID_N, 768);
  reduce_mix_kernel<<<dim3(3, 256), 256, 0, stream>>>(P, Omega, b1, xt2, nullptr, HID_N, 768);

  // layer 2: 256 x 6016 @ 6016 x 752
  gemm_splitk<<<dim3(12, SPLITK), 256, 0, stream>>>(xt2, w2, P, K2_N, HID_N, 768);
  reduce_mix_kernel<<<dim3(3, 256), 256, 0, stream>>>(P, Omega, b2, xt3, nullptr, HID_N, 768);

  // layer 3: 256 x 6016 @ 6016 x 512
  gemm_splitk<<<dim3(8, SPLITK), 256, 0, stream>>>(xt3, w3, P, K2_N, 512, 512);
  reduce_mix_kernel<<<dim3(2, 256), 256, 0, stream>>>(P, Omega, b3, nullptr, (float*)d_out, 512, 512);
}